// Round 7
// baseline (402.241 us; speedup 1.0000x reference)
//
#include <hip/hip_runtime.h>
#include <hip/hip_bf16.h>

#define N_NODES 50000
#define BSHIFT  6
#define BSIZE   64                       // nodes per bucket
#define NBUCK   ((N_NODES + BSIZE - 1) / BSIZE)   // 782

using short8  = __attribute__((ext_vector_type(8))) short;
using floatx4 = __attribute__((ext_vector_type(4))) float;

__device__ inline short f32_to_bf16_bits(float f) {
    __hip_bfloat16 h = __float2bfloat16(f);
    return *reinterpret_cast<short*>(&h);
}

// ---------------- MFMA GEMM: C_bf16[M,N] = A[M,K] @ W[K,N] + b ----------------
template<int K, int N, bool A_F32>
__global__ __launch_bounds__(256) void mfma_gemm(const void* __restrict__ Araw,
                                                 const short* __restrict__ WT,
                                                 const float* __restrict__ bias,
                                                 short* __restrict__ C, int M)
{
    constexpr int CW  = N / 4;
    constexpr int TPW = CW / 16;
    constexpr int KS  = K / 32;

    const int tid  = threadIdx.x;
    const int wave = tid >> 6;
    const int lane = tid & 63;
    const int l15  = lane & 15;
    const int lk   = (lane >> 4) * 8;
    const int n0   = wave * CW;

    short8 bfrag[TPW][KS];
#pragma unroll
    for (int t = 0; t < TPW; ++t)
#pragma unroll
        for (int ks = 0; ks < KS; ++ks)
            bfrag[t][ks] = *reinterpret_cast<const short8*>(
                &WT[(size_t)(n0 + t * 16 + l15) * K + ks * 32 + lk]);

    float bv[TPW];
#pragma unroll
    for (int t = 0; t < TPW; ++t) bv[t] = bias[n0 + t * 16 + l15];

    const float* Af = (const float*)Araw;
    const short* Ab = (const short*)Araw;

    const int rbase = blockIdx.x * 64;
#pragma unroll
    for (int s = 0; s < 4; ++s) {
        const int r0 = rbase + s * 16;
        if (r0 >= M) break;

        floatx4 acc[TPW];
#pragma unroll
        for (int t = 0; t < TPW; ++t) acc[t] = (floatx4){0.f, 0.f, 0.f, 0.f};

        const int arow = min(r0 + l15, M - 1);
#pragma unroll
        for (int ks = 0; ks < KS; ++ks) {
            short8 af;
            if (A_F32) {
                const float4 v0 = *reinterpret_cast<const float4*>(&Af[(size_t)arow * K + ks * 32 + lk]);
                const float4 v1 = *reinterpret_cast<const float4*>(&Af[(size_t)arow * K + ks * 32 + lk + 4]);
                af[0] = f32_to_bf16_bits(v0.x); af[1] = f32_to_bf16_bits(v0.y);
                af[2] = f32_to_bf16_bits(v0.z); af[3] = f32_to_bf16_bits(v0.w);
                af[4] = f32_to_bf16_bits(v1.x); af[5] = f32_to_bf16_bits(v1.y);
                af[6] = f32_to_bf16_bits(v1.z); af[7] = f32_to_bf16_bits(v1.w);
            } else {
                af = *reinterpret_cast<const short8*>(&Ab[(size_t)arow * K + ks * 32 + lk]);
            }
#pragma unroll
            for (int t = 0; t < TPW; ++t)
                acc[t] = __builtin_amdgcn_mfma_f32_16x16x32_bf16(af, bfrag[t][ks], acc[t], 0, 0, 0);
        }

        const int rowg = (lane >> 4) * 4;
#pragma unroll
        for (int t = 0; t < TPW; ++t)
#pragma unroll
            for (int j = 0; j < 4; ++j) {
                const int gr = r0 + rowg + j;
                if (gr < M)
                    C[(size_t)gr * N + n0 + t * 16 + l15] = f32_to_bf16_bits(acc[t][j] + bv[t]);
            }
    }
}

// ---------------- all three W -> W^T bf16 in one kernel ----------------
__global__ __launch_bounds__(256) void wt_all(const float* __restrict__ W1, short* __restrict__ WT1,
                                              const float* __restrict__ W2, short* __restrict__ WT2,
                                              const float* __restrict__ W3, short* __restrict__ WT3)
{
    const int i = blockIdx.x * 256 + threadIdx.x;
    if (i < 256 * 128) {
        const int k = i >> 7, n = i & 127;
        WT1[(size_t)n * 256 + k] = f32_to_bf16_bits(W1[i]);
    }
    if (i < 128 * 128) {
        const int k = i >> 7, n = i & 127;
        WT2[(size_t)n * 128 + k] = f32_to_bf16_bits(W2[i]);
    }
    if (i < 128 * 64) {
        const int k = i >> 6, n = i & 63;
        WT3[(size_t)n * 128 + k] = f32_to_bf16_bits(W3[i]);
    }
}

// ---------------- CSR build ----------------
__global__ __launch_bounds__(256) void hist_kernel(const int* __restrict__ dst,
                                                   int* __restrict__ deg, int E)
{
    const int i = blockIdx.x * 256 + threadIdx.x;
    if (i < E) atomicAdd(&deg[dst[i]], 1);
}

__global__ __launch_bounds__(256) void scan_partial(const int* __restrict__ deg,
                                                    int* __restrict__ partial, int n)
{
    __shared__ int red[4];
    const int t = threadIdx.x;
    const int i = blockIdx.x * 256 + t;
    int v = (i < n) ? deg[i] : 0;
#pragma unroll
    for (int off = 32; off > 0; off >>= 1) v += __shfl_down(v, off, 64);
    if ((t & 63) == 0) red[t >> 6] = v;
    __syncthreads();
    if (t == 0) partial[blockIdx.x] = red[0] + red[1] + red[2] + red[3];
}

__global__ __launch_bounds__(256) void scan_offsets(int* __restrict__ partial, int nb)
{
    __shared__ int s[256];
    const int t = threadIdx.x;
    const int v = (t < nb) ? partial[t] : 0;
    s[t] = v;
    __syncthreads();
#pragma unroll
    for (int off = 1; off < 256; off <<= 1) {
        const int tmp = (t >= off) ? s[t - off] : 0;
        __syncthreads();
        s[t] += tmp;
        __syncthreads();
    }
    if (t < nb) partial[t] = s[t] - v;
}

// row_ptr + bucket bases (bcur) — global cursor array no longer needed.
__global__ __launch_bounds__(256) void scan_final(const int* __restrict__ deg,
                                                  const int* __restrict__ partial,
                                                  int* __restrict__ row_ptr,
                                                  int* __restrict__ bcur, int n, int E)
{
    __shared__ int s[256];
    const int t = threadIdx.x;
    const int i = blockIdx.x * 256 + t;
    const int v = (i < n) ? deg[i] : 0;
    s[t] = v;
    __syncthreads();
#pragma unroll
    for (int off = 1; off < 256; off <<= 1) {
        const int tmp = (t >= off) ? s[t - off] : 0;
        __syncthreads();
        s[t] += tmp;
        __syncthreads();
    }
    const int excl = s[t] - v + partial[blockIdx.x];
    if (i < n) {
        row_ptr[i] = excl;
        if ((i & (BSIZE - 1)) == 0) bcur[i >> BSHIFT] = excl;
    }
    if (i == 0) row_ptr[n] = E;
}

// Pass 1: coarse bin by dst>>6 into bucket-contiguous tmp regions.
// tmp.x = (src << 16) | (dst & 63), tmp.y = w bits.
__global__ __launch_bounds__(256) void bin_kernel(const int* __restrict__ src,
                                                  const int* __restrict__ dst,
                                                  const float* __restrict__ w,
                                                  int* __restrict__ bcur,
                                                  int2* __restrict__ tmp, int E)
{
    const int i = blockIdx.x * 256 + threadIdx.x;
    if (i < E) {
        const int d   = dst[i];
        const int pos = atomicAdd(&bcur[d >> BSHIFT], 1);
        int2 e;
        e.x = (int)(((unsigned)src[i] << 16) | (unsigned)(d & (BSIZE - 1)));
        e.y = __float_as_int(w[i]);
        tmp[pos] = e;
    }
}

// Pass 2: one block per bucket; LDS cursors; localized writes into csr_ew.
__global__ __launch_bounds__(256) void fine_fill(const int2* __restrict__ tmp,
                                                 const int* __restrict__ row_ptr,
                                                 int2* __restrict__ csr_ew, int M)
{
    __shared__ int cur[BSIZE];
    const int b   = blockIdx.x;
    const int nb0 = b << BSHIFT;
    const int t   = threadIdx.x;
    if (t < BSIZE) cur[t] = row_ptr[min(nb0 + t, M)];
    __syncthreads();

    const int rbeg = row_ptr[min(nb0, M)];
    const int rend = row_ptr[min(nb0 + BSIZE, M)];
    for (int i = rbeg + t; i < rend; i += 256) {
        const int2 e = tmp[i];
        const unsigned ex = (unsigned)e.x;
        const int dl   = (int)(ex & (BSIZE - 1));
        const int srcn = (int)(ex >> 16);
        const int pos  = atomicAdd(&cur[dl], 1);
        csr_ew[pos] = make_int2(srcn, e.y);
    }
}

// ---------------- pull (bf16 h, D=128): one wave per node ----------------
template<bool RELU>
__global__ __launch_bounds__(256) void pull128_bf(const unsigned int* __restrict__ h,
                                                  const int* __restrict__ row_ptr,
                                                  const int2* __restrict__ csr_ew,
                                                  unsigned int* __restrict__ out, int n_nodes)
{
    const int wave = threadIdx.x >> 6;
    const int lane = threadIdx.x & 63;
    const int node = blockIdx.x * 4 + wave;
    if (node >= n_nodes) return;

    const int beg = row_ptr[node];
    const int end = row_ptr[node + 1];

    float ax0 = 0.f, ay0 = 0.f, ax1 = 0.f, ay1 = 0.f;
    float ax2 = 0.f, ay2 = 0.f, ax3 = 0.f, ay3 = 0.f;

    for (int c = beg; c < end; c += 64) {
        const int idx = c + lane;
        int2 ew = make_int2(0, 0);
        if (idx < end) ew = csr_ew[idx];
        const int cnt = min(64, end - c);

        int j = 0;
        for (; j + 4 <= cnt; j += 4) {
            const int   s0 = __shfl(ew.x, j);
            const int   s1 = __shfl(ew.x, j + 1);
            const int   s2 = __shfl(ew.x, j + 2);
            const int   s3 = __shfl(ew.x, j + 3);
            const float w0 = __int_as_float(__shfl(ew.y, j));
            const float w1 = __int_as_float(__shfl(ew.y, j + 1));
            const float w2 = __int_as_float(__shfl(ew.y, j + 2));
            const float w3 = __int_as_float(__shfl(ew.y, j + 3));
            const unsigned int p0 = h[(size_t)s0 * 64 + lane];
            const unsigned int p1 = h[(size_t)s1 * 64 + lane];
            const unsigned int p2 = h[(size_t)s2 * 64 + lane];
            const unsigned int p3 = h[(size_t)s3 * 64 + lane];
            ax0 = fmaf(__int_as_float(p0 << 16), w0, ax0);
            ay0 = fmaf(__int_as_float(p0 & 0xffff0000u), w0, ay0);
            ax1 = fmaf(__int_as_float(p1 << 16), w1, ax1);
            ay1 = fmaf(__int_as_float(p1 & 0xffff0000u), w1, ay1);
            ax2 = fmaf(__int_as_float(p2 << 16), w2, ax2);
            ay2 = fmaf(__int_as_float(p2 & 0xffff0000u), w2, ay2);
            ax3 = fmaf(__int_as_float(p3 << 16), w3, ax3);
            ay3 = fmaf(__int_as_float(p3 & 0xffff0000u), w3, ay3);
        }
        for (; j < cnt; ++j) {
            const int   s0 = __shfl(ew.x, j);
            const float w0 = __int_as_float(__shfl(ew.y, j));
            const unsigned int p0 = h[(size_t)s0 * 64 + lane];
            ax0 = fmaf(__int_as_float(p0 << 16), w0, ax0);
            ay0 = fmaf(__int_as_float(p0 & 0xffff0000u), w0, ay0);
        }
    }

    float ax = (ax0 + ax1) + (ax2 + ax3);
    float ay = (ay0 + ay1) + (ay2 + ay3);
    if (RELU) { ax = fmaxf(ax, 0.f); ay = fmaxf(ay, 0.f); }
    const unsigned int lo = (unsigned short)f32_to_bf16_bits(ax);
    const unsigned int hi = (unsigned short)f32_to_bf16_bits(ay);
    out[(size_t)node * 64 + lane] = lo | (hi << 16);
}

// ---------------- pull (bf16 h, D=64): two nodes per wave, f32 out ----------------
__global__ __launch_bounds__(256) void pull64_bf(const unsigned int* __restrict__ h,
                                                 const int* __restrict__ row_ptr,
                                                 const int2* __restrict__ csr_ew,
                                                 float2* __restrict__ out, int n_nodes)
{
    const int wave = threadIdx.x >> 6;
    const int lane = threadIdx.x & 63;
    const int half = lane >> 5;
    const int l32  = lane & 31;
    const int node = blockIdx.x * 8 + wave * 2 + half;
    if (node >= n_nodes) return;

    const int beg = row_ptr[node];
    const int end = row_ptr[node + 1];

    float ax0 = 0.f, ay0 = 0.f, ax1 = 0.f, ay1 = 0.f;
    float ax2 = 0.f, ay2 = 0.f, ax3 = 0.f, ay3 = 0.f;

    for (int c = beg; c < end; c += 32) {
        const int idx = c + l32;
        int2 ew = make_int2(0, 0);
        if (idx < end) ew = csr_ew[idx];
        const int cnt = min(32, end - c);

        int j = 0;
        for (; j + 4 <= cnt; j += 4) {
            const int   s0 = __shfl(ew.x, j, 32);
            const int   s1 = __shfl(ew.x, j + 1, 32);
            const int   s2 = __shfl(ew.x, j + 2, 32);
            const int   s3 = __shfl(ew.x, j + 3, 32);
            const float w0 = __int_as_float(__shfl(ew.y, j, 32));
            const float w1 = __int_as_float(__shfl(ew.y, j + 1, 32));
            const float w2 = __int_as_float(__shfl(ew.y, j + 2, 32));
            const float w3 = __int_as_float(__shfl(ew.y, j + 3, 32));
            const unsigned int p0 = h[(size_t)s0 * 32 + l32];
            const unsigned int p1 = h[(size_t)s1 * 32 + l32];
            const unsigned int p2 = h[(size_t)s2 * 32 + l32];
            const unsigned int p3 = h[(size_t)s3 * 32 + l32];
            ax0 = fmaf(__int_as_float(p0 << 16), w0, ax0);
            ay0 = fmaf(__int_as_float(p0 & 0xffff0000u), w0, ay0);
            ax1 = fmaf(__int_as_float(p1 << 16), w1, ax1);
            ay1 = fmaf(__int_as_float(p1 & 0xffff0000u), w1, ay1);
            ax2 = fmaf(__int_as_float(p2 << 16), w2, ax2);
            ay2 = fmaf(__int_as_float(p2 & 0xffff0000u), w2, ay2);
            ax3 = fmaf(__int_as_float(p3 << 16), w3, ax3);
            ay3 = fmaf(__int_as_float(p3 & 0xffff0000u), w3, ay3);
        }
        for (; j < cnt; ++j) {
            const int   s0 = __shfl(ew.x, j, 32);
            const float w0 = __int_as_float(__shfl(ew.y, j, 32));
            const unsigned int p0 = h[(size_t)s0 * 32 + l32];
            ax0 = fmaf(__int_as_float(p0 << 16), w0, ax0);
            ay0 = fmaf(__int_as_float(p0 & 0xffff0000u), w0, ay0);
        }
    }

    const float ax = (ax0 + ax1) + (ax2 + ax3);
    const float ay = (ay0 + ay1) + (ay2 + ay3);
    out[(size_t)node * 32 + l32] = make_float2(ax, ay);
}

extern "C" void kernel_launch(void* const* d_in, const int* in_sizes, int n_in,
                              void* d_out, int out_size, void* d_ws, size_t ws_size,
                              hipStream_t stream)
{
    const float* x   = (const float*)d_in[0];
    const int*   src = (const int*)  d_in[1];
    const int*   dst = (const int*)  d_in[2];
    const float* w   = (const float*)d_in[3];
    const float* W1  = (const float*)d_in[4];
    const float* b1  = (const float*)d_in[5];
    const float* W2  = (const float*)d_in[6];
    const float* b2  = (const float*)d_in[7];
    const float* W3  = (const float*)d_in[8];
    const float* b3  = (const float*)d_in[9];

    const int E = in_sizes[1];
    const int M = N_NODES;

    // workspace layout
    short* hA  = (short*)d_ws;                    // M*128 bf16
    short* hB  = hA + (size_t)M * 128;            // M*128 bf16
    short* WT1 = hB + (size_t)M * 128;            // 128*256
    short* WT2 = WT1 + 128 * 256;                 // 128*128
    short* WT3 = WT2 + 128 * 128;                 // 64*128
    int2*  csr_ew  = (int2*)(WT3 + 64 * 128);     // E pairs
    int2*  tmp_ew  = csr_ew + E;                  // E pairs (binned)
    int*   row_ptr = (int*)(tmp_ew + E);          // 50048
    int*   bcur    = row_ptr + 50048;             // 782 -> pad 1024
    int*   deg     = bcur + 1024;                 // 50048
    int*   partial = deg + 50048;                 // 256

    const int eb = (E + 255) / 256;
    const int nb = (M + 255) / 256;
    const int gemm_blocks = (M + 63) / 64;

    // ---- weights + CSR build ----
    wt_all<<<(256 * 128 + 255) / 256, 256, 0, stream>>>(W1, WT1, W2, WT2, W3, WT3);
    hipMemsetAsync(deg, 0, (size_t)M * sizeof(int), stream);
    hist_kernel<<<eb, 256, 0, stream>>>(dst, deg, E);
    scan_partial<<<nb, 256, 0, stream>>>(deg, partial, M);
    scan_offsets<<<1, 256, 0, stream>>>(partial, nb);
    scan_final<<<nb, 256, 0, stream>>>(deg, partial, row_ptr, bcur, M, E);
    bin_kernel<<<eb, 256, 0, stream>>>(src, dst, w, bcur, tmp_ew, E);
    fine_fill<<<NBUCK, 256, 0, stream>>>(tmp_ew, row_ptr, csr_ew, M);

    // ---- Layer 1 ----
    mfma_gemm<256, 128, true><<<gemm_blocks, 256, 0, stream>>>(x, WT1, b1, hA, M);
    pull128_bf<true><<<(M + 3) / 4, 256, 0, stream>>>((const unsigned int*)hA, row_ptr, csr_ew,
                                                      (unsigned int*)hB, M);
    // ---- Layer 2 ----
    mfma_gemm<128, 128, false><<<gemm_blocks, 256, 0, stream>>>(hB, WT2, b2, hA, M);
    pull128_bf<true><<<(M + 3) / 4, 256, 0, stream>>>((const unsigned int*)hA, row_ptr, csr_ew,
                                                      (unsigned int*)hB, M);
    // ---- Layer 3 ----
    mfma_gemm<128, 64, false><<<gemm_blocks, 256, 0, stream>>>(hB, WT3, b3, hA, M);
    pull64_bf<<<(M + 7) / 8, 256, 0, stream>>>((const unsigned int*)hA, row_ptr, csr_ew,
                                               (float2*)d_out, M);
}

// Round 8
// 226.321 us; speedup vs baseline: 1.7773x; 1.7773x over previous
//
#include <hip/hip_runtime.h>
#include <hip/hip_bf16.h>

#define N_NODES 50000
#define BSHIFT  6
#define BSIZE   64
#define NBUCK   ((N_NODES + BSIZE - 1) / BSIZE)   // 782
#define BIN_BLOCKS 64

using short8  = __attribute__((ext_vector_type(8))) short;
using floatx4 = __attribute__((ext_vector_type(4))) float;

__device__ inline short f32_to_bf16_bits(float f) {
    __hip_bfloat16 h = __float2bfloat16(f);
    return *reinterpret_cast<short*>(&h);
}

// ---------------- MFMA GEMM: C_bf16[M,N] = A[M,K] @ W[K,N] + b ----------------
template<int K, int N, bool A_F32>
__global__ __launch_bounds__(256) void mfma_gemm(const void* __restrict__ Araw,
                                                 const short* __restrict__ WT,
                                                 const float* __restrict__ bias,
                                                 short* __restrict__ C, int M)
{
    constexpr int CW  = N / 4;
    constexpr int TPW = CW / 16;
    constexpr int KS  = K / 32;

    const int tid  = threadIdx.x;
    const int wave = tid >> 6;
    const int lane = tid & 63;
    const int l15  = lane & 15;
    const int lk   = (lane >> 4) * 8;
    const int n0   = wave * CW;

    short8 bfrag[TPW][KS];
#pragma unroll
    for (int t = 0; t < TPW; ++t)
#pragma unroll
        for (int ks = 0; ks < KS; ++ks)
            bfrag[t][ks] = *reinterpret_cast<const short8*>(
                &WT[(size_t)(n0 + t * 16 + l15) * K + ks * 32 + lk]);

    float bv[TPW];
#pragma unroll
    for (int t = 0; t < TPW; ++t) bv[t] = bias[n0 + t * 16 + l15];

    const float* Af = (const float*)Araw;
    const short* Ab = (const short*)Araw;

    const int rbase = blockIdx.x * 64;
#pragma unroll
    for (int s = 0; s < 4; ++s) {
        const int r0 = rbase + s * 16;
        if (r0 >= M) break;

        floatx4 acc[TPW];
#pragma unroll
        for (int t = 0; t < TPW; ++t) acc[t] = (floatx4){0.f, 0.f, 0.f, 0.f};

        const int arow = min(r0 + l15, M - 1);
#pragma unroll
        for (int ks = 0; ks < KS; ++ks) {
            short8 af;
            if (A_F32) {
                const float4 v0 = *reinterpret_cast<const float4*>(&Af[(size_t)arow * K + ks * 32 + lk]);
                const float4 v1 = *reinterpret_cast<const float4*>(&Af[(size_t)arow * K + ks * 32 + lk + 4]);
                af[0] = f32_to_bf16_bits(v0.x); af[1] = f32_to_bf16_bits(v0.y);
                af[2] = f32_to_bf16_bits(v0.z); af[3] = f32_to_bf16_bits(v0.w);
                af[4] = f32_to_bf16_bits(v1.x); af[5] = f32_to_bf16_bits(v1.y);
                af[6] = f32_to_bf16_bits(v1.z); af[7] = f32_to_bf16_bits(v1.w);
            } else {
                af = *reinterpret_cast<const short8*>(&Ab[(size_t)arow * K + ks * 32 + lk]);
            }
#pragma unroll
            for (int t = 0; t < TPW; ++t)
                acc[t] = __builtin_amdgcn_mfma_f32_16x16x32_bf16(af, bfrag[t][ks], acc[t], 0, 0, 0);
        }

        const int rowg = (lane >> 4) * 4;
#pragma unroll
        for (int t = 0; t < TPW; ++t)
#pragma unroll
            for (int j = 0; j < 4; ++j) {
                const int gr = r0 + rowg + j;
                if (gr < M)
                    C[(size_t)gr * N + n0 + t * 16 + l15] = f32_to_bf16_bits(acc[t][j] + bv[t]);
            }
    }
}

// ---------------- all three W -> W^T bf16 in one kernel ----------------
__global__ __launch_bounds__(256) void wt_all(const float* __restrict__ W1, short* __restrict__ WT1,
                                              const float* __restrict__ W2, short* __restrict__ WT2,
                                              const float* __restrict__ W3, short* __restrict__ WT3)
{
    const int i = blockIdx.x * 256 + threadIdx.x;
    if (i < 256 * 128) {
        const int k = i >> 7, n = i & 127;
        WT1[(size_t)n * 256 + k] = f32_to_bf16_bits(W1[i]);
    }
    if (i < 128 * 128) {
        const int k = i >> 7, n = i & 127;
        WT2[(size_t)n * 128 + k] = f32_to_bf16_bits(W2[i]);
    }
    if (i < 128 * 64) {
        const int k = i >> 6, n = i & 63;
        WT3[(size_t)n * 128 + k] = f32_to_bf16_bits(W3[i]);
    }
}

// ================= CSR build: block-aggregated counting sort (no global atomics) =================

// Pass A: per-block LDS histogram of dst>>6 over its edge chunk.
__global__ __launch_bounds__(256) void bin_hist(const int* __restrict__ dst,
                                                int* __restrict__ hist_g, int E)
{
    __shared__ int hist[NBUCK];
    for (int t = threadIdx.x; t < NBUCK; t += 256) hist[t] = 0;
    __syncthreads();
    const int chunk = (E + BIN_BLOCKS - 1) / BIN_BLOCKS;
    const int beg = blockIdx.x * chunk;
    const int end = min(beg + chunk, E);
    for (int i = beg + threadIdx.x; i < end; i += 256)
        atomicAdd(&hist[dst[i] >> BSHIFT], 1);
    __syncthreads();
    for (int t = threadIdx.x; t < NBUCK; t += 256)
        hist_g[blockIdx.x * NBUCK + t] = hist[t];
}

// Pass B (1 block): blockbase[blk][b] = within-bucket prefix over blocks;
// bucket_base[b] = exclusive scan of bucket totals; bucket_base[NBUCK] = E.
__global__ __launch_bounds__(256) void bin_scan(const int* __restrict__ hist_g,
                                                int* __restrict__ blockbase,
                                                int* __restrict__ bucket_base)
{
    __shared__ int tot[NBUCK];
    __shared__ int psum[256];
    const int t = threadIdx.x;

    for (int b = t; b < NBUCK; b += 256) {
        int run = 0;
        for (int blk = 0; blk < BIN_BLOCKS; ++blk) {
            blockbase[blk * NBUCK + b] = run;
            run += hist_g[blk * NBUCK + b];
        }
        tot[b] = run;
    }
    __syncthreads();

    // exclusive scan over tot[0..NBUCK): 4 slots per thread
    int vals[4];
    int s = 0;
#pragma unroll
    for (int j = 0; j < 4; ++j) {
        const int idx = t * 4 + j;
        vals[j] = (idx < NBUCK) ? tot[idx] : 0;
        s += vals[j];
    }
    psum[t] = s;
    __syncthreads();
#pragma unroll
    for (int off = 1; off < 256; off <<= 1) {
        const int tmp = (t >= off) ? psum[t - off] : 0;
        __syncthreads();
        psum[t] += tmp;
        __syncthreads();
    }
    int run = psum[t] - s;   // exclusive
#pragma unroll
    for (int j = 0; j < 4; ++j) {
        const int idx = t * 4 + j;
        if (idx < NBUCK) bucket_base[idx] = run;
        run += vals[j];
    }
    if (t == 255) bucket_base[NBUCK] = run;   // == E
}

// Pass C: re-read chunk, LDS cursors (seeded from bases), write packed tmp.
// tmp.x = (src << 6) | (dst & 63), tmp.y = w bits.
__global__ __launch_bounds__(256) void bin_write(const int* __restrict__ src,
                                                 const int* __restrict__ dst,
                                                 const float* __restrict__ w,
                                                 const int* __restrict__ blockbase,
                                                 const int* __restrict__ bucket_base,
                                                 int2* __restrict__ tmp, int E)
{
    __shared__ int cur[NBUCK];
    for (int t = threadIdx.x; t < NBUCK; t += 256)
        cur[t] = bucket_base[t] + blockbase[blockIdx.x * NBUCK + t];
    __syncthreads();
    const int chunk = (E + BIN_BLOCKS - 1) / BIN_BLOCKS;
    const int beg = blockIdx.x * chunk;
    const int end = min(beg + chunk, E);
    for (int i = beg + threadIdx.x; i < end; i += 256) {
        const int d = dst[i];
        const int pos = atomicAdd(&cur[d >> BSHIFT], 1);
        tmp[pos] = make_int2((src[i] << BSHIFT) | (d & (BSIZE - 1)), __float_as_int(w[i]));
    }
}

// Pass D: one block per bucket. Emits row_ptr for its 64 nodes + node-sorted csr_ew.
__global__ __launch_bounds__(256) void fine_fill2(const int2* __restrict__ tmp,
                                                  const int* __restrict__ bucket_base,
                                                  int2* __restrict__ csr_ew,
                                                  int* __restrict__ row_ptr)
{
    __shared__ int hist[BSIZE];
    __shared__ int basel[BSIZE];
    const int b    = blockIdx.x;
    const int t    = threadIdx.x;
    const int rbeg = bucket_base[b];
    const int rend = bucket_base[b + 1];

    if (t < BSIZE) hist[t] = 0;
    __syncthreads();
    for (int i = rbeg + t; i < rend; i += 256)
        atomicAdd(&hist[((unsigned)tmp[i].x) & (BSIZE - 1)], 1);
    __syncthreads();

    if (t < BSIZE) {
        const int v = hist[t];
        int inc = v;
#pragma unroll
        for (int off = 1; off < BSIZE; off <<= 1) {
            const int u = __shfl_up(inc, off, 64);
            if (t >= off) inc += u;
        }
        const int excl = rbeg + inc - v;
        basel[t] = excl;
        const int node = (b << BSHIFT) + t;
        if (node < N_NODES) row_ptr[node] = excl;
        if (b == NBUCK - 1 && t == 0) row_ptr[N_NODES] = bucket_base[NBUCK];
    }
    __syncthreads();

    for (int i = rbeg + t; i < rend; i += 256) {
        const int2 e = tmp[i];
        const unsigned ex = (unsigned)e.x;
        const int pos = atomicAdd(&basel[ex & (BSIZE - 1)], 1);
        csr_ew[pos] = make_int2((int)(ex >> BSHIFT), e.y);
    }
}

// ---------------- pull (bf16 h, D=128): one wave per node ----------------
template<bool RELU>
__global__ __launch_bounds__(256) void pull128_bf(const unsigned int* __restrict__ h,
                                                  const int* __restrict__ row_ptr,
                                                  const int2* __restrict__ csr_ew,
                                                  unsigned int* __restrict__ out, int n_nodes)
{
    const int wave = threadIdx.x >> 6;
    const int lane = threadIdx.x & 63;
    const int node = blockIdx.x * 4 + wave;
    if (node >= n_nodes) return;

    const int beg = row_ptr[node];
    const int end = row_ptr[node + 1];

    float ax0 = 0.f, ay0 = 0.f, ax1 = 0.f, ay1 = 0.f;
    float ax2 = 0.f, ay2 = 0.f, ax3 = 0.f, ay3 = 0.f;

    for (int c = beg; c < end; c += 64) {
        const int idx = c + lane;
        int2 ew = make_int2(0, 0);
        if (idx < end) ew = csr_ew[idx];
        const int cnt = min(64, end - c);

        int j = 0;
        for (; j + 4 <= cnt; j += 4) {
            const int   s0 = __shfl(ew.x, j);
            const int   s1 = __shfl(ew.x, j + 1);
            const int   s2 = __shfl(ew.x, j + 2);
            const int   s3 = __shfl(ew.x, j + 3);
            const float w0 = __int_as_float(__shfl(ew.y, j));
            const float w1 = __int_as_float(__shfl(ew.y, j + 1));
            const float w2 = __int_as_float(__shfl(ew.y, j + 2));
            const float w3 = __int_as_float(__shfl(ew.y, j + 3));
            const unsigned int p0 = h[(size_t)s0 * 64 + lane];
            const unsigned int p1 = h[(size_t)s1 * 64 + lane];
            const unsigned int p2 = h[(size_t)s2 * 64 + lane];
            const unsigned int p3 = h[(size_t)s3 * 64 + lane];
            ax0 = fmaf(__int_as_float(p0 << 16), w0, ax0);
            ay0 = fmaf(__int_as_float(p0 & 0xffff0000u), w0, ay0);
            ax1 = fmaf(__int_as_float(p1 << 16), w1, ax1);
            ay1 = fmaf(__int_as_float(p1 & 0xffff0000u), w1, ay1);
            ax2 = fmaf(__int_as_float(p2 << 16), w2, ax2);
            ay2 = fmaf(__int_as_float(p2 & 0xffff0000u), w2, ay2);
            ax3 = fmaf(__int_as_float(p3 << 16), w3, ax3);
            ay3 = fmaf(__int_as_float(p3 & 0xffff0000u), w3, ay3);
        }
        for (; j < cnt; ++j) {
            const int   s0 = __shfl(ew.x, j);
            const float w0 = __int_as_float(__shfl(ew.y, j));
            const unsigned int p0 = h[(size_t)s0 * 64 + lane];
            ax0 = fmaf(__int_as_float(p0 << 16), w0, ax0);
            ay0 = fmaf(__int_as_float(p0 & 0xffff0000u), w0, ay0);
        }
    }

    float ax = (ax0 + ax1) + (ax2 + ax3);
    float ay = (ay0 + ay1) + (ay2 + ay3);
    if (RELU) { ax = fmaxf(ax, 0.f); ay = fmaxf(ay, 0.f); }
    const unsigned int lo = (unsigned short)f32_to_bf16_bits(ax);
    const unsigned int hi = (unsigned short)f32_to_bf16_bits(ay);
    out[(size_t)node * 64 + lane] = lo | (hi << 16);
}

// ---------------- pull (bf16 h, D=64): two nodes per wave, f32 out ----------------
__global__ __launch_bounds__(256) void pull64_bf(const unsigned int* __restrict__ h,
                                                 const int* __restrict__ row_ptr,
                                                 const int2* __restrict__ csr_ew,
                                                 float2* __restrict__ out, int n_nodes)
{
    const int wave = threadIdx.x >> 6;
    const int lane = threadIdx.x & 63;
    const int half = lane >> 5;
    const int l32  = lane & 31;
    const int node = blockIdx.x * 8 + wave * 2 + half;
    if (node >= n_nodes) return;

    const int beg = row_ptr[node];
    const int end = row_ptr[node + 1];

    float ax0 = 0.f, ay0 = 0.f, ax1 = 0.f, ay1 = 0.f;
    float ax2 = 0.f, ay2 = 0.f, ax3 = 0.f, ay3 = 0.f;

    for (int c = beg; c < end; c += 32) {
        const int idx = c + l32;
        int2 ew = make_int2(0, 0);
        if (idx < end) ew = csr_ew[idx];
        const int cnt = min(32, end - c);

        int j = 0;
        for (; j + 4 <= cnt; j += 4) {
            const int   s0 = __shfl(ew.x, j, 32);
            const int   s1 = __shfl(ew.x, j + 1, 32);
            const int   s2 = __shfl(ew.x, j + 2, 32);
            const int   s3 = __shfl(ew.x, j + 3, 32);
            const float w0 = __int_as_float(__shfl(ew.y, j, 32));
            const float w1 = __int_as_float(__shfl(ew.y, j + 1, 32));
            const float w2 = __int_as_float(__shfl(ew.y, j + 2, 32));
            const float w3 = __int_as_float(__shfl(ew.y, j + 3, 32));
            const unsigned int p0 = h[(size_t)s0 * 32 + l32];
            const unsigned int p1 = h[(size_t)s1 * 32 + l32];
            const unsigned int p2 = h[(size_t)s2 * 32 + l32];
            const unsigned int p3 = h[(size_t)s3 * 32 + l32];
            ax0 = fmaf(__int_as_float(p0 << 16), w0, ax0);
            ay0 = fmaf(__int_as_float(p0 & 0xffff0000u), w0, ay0);
            ax1 = fmaf(__int_as_float(p1 << 16), w1, ax1);
            ay1 = fmaf(__int_as_float(p1 & 0xffff0000u), w1, ay1);
            ax2 = fmaf(__int_as_float(p2 << 16), w2, ax2);
            ay2 = fmaf(__int_as_float(p2 & 0xffff0000u), w2, ay2);
            ax3 = fmaf(__int_as_float(p3 << 16), w3, ax3);
            ay3 = fmaf(__int_as_float(p3 & 0xffff0000u), w3, ay3);
        }
        for (; j < cnt; ++j) {
            const int   s0 = __shfl(ew.x, j, 32);
            const float w0 = __int_as_float(__shfl(ew.y, j, 32));
            const unsigned int p0 = h[(size_t)s0 * 32 + l32];
            ax0 = fmaf(__int_as_float(p0 << 16), w0, ax0);
            ay0 = fmaf(__int_as_float(p0 & 0xffff0000u), w0, ay0);
        }
    }

    const float ax = (ax0 + ax1) + (ax2 + ax3);
    const float ay = (ay0 + ay1) + (ay2 + ay3);
    out[(size_t)node * 32 + l32] = make_float2(ax, ay);
}

extern "C" void kernel_launch(void* const* d_in, const int* in_sizes, int n_in,
                              void* d_out, int out_size, void* d_ws, size_t ws_size,
                              hipStream_t stream)
{
    const float* x   = (const float*)d_in[0];
    const int*   src = (const int*)  d_in[1];
    const int*   dst = (const int*)  d_in[2];
    const float* w   = (const float*)d_in[3];
    const float* W1  = (const float*)d_in[4];
    const float* b1  = (const float*)d_in[5];
    const float* W2  = (const float*)d_in[6];
    const float* b2  = (const float*)d_in[7];
    const float* W3  = (const float*)d_in[8];
    const float* b3  = (const float*)d_in[9];

    const int E = in_sizes[1];
    const int M = N_NODES;

    // workspace layout
    short* hA  = (short*)d_ws;                        // M*128 bf16
    short* hB  = hA + (size_t)M * 128;                // M*128 bf16
    short* WT1 = hB + (size_t)M * 128;                // 128*256
    short* WT2 = WT1 + 128 * 256;                     // 128*128
    short* WT3 = WT2 + 128 * 128;                     // 64*128
    int2*  csr_ew      = (int2*)(WT3 + 64 * 128);     // E pairs
    int2*  tmp_ew      = csr_ew + E;                  // E pairs
    int*   row_ptr     = (int*)(tmp_ew + E);          // 50048
    int*   hist_g      = row_ptr + 50048;             // 64*782 -> pad 50048
    int*   blockbase   = hist_g + 50048;              // 64*782 -> pad 50048
    int*   bucket_base = blockbase + 50048;           // 783 -> pad 1024

    const int gemm_blocks = (M + 63) / 64;

    // ---- weights + CSR build (no global atomics) ----
    wt_all<<<(256 * 128 + 255) / 256, 256, 0, stream>>>(W1, WT1, W2, WT2, W3, WT3);
    bin_hist<<<BIN_BLOCKS, 256, 0, stream>>>(dst, hist_g, E);
    bin_scan<<<1, 256, 0, stream>>>(hist_g, blockbase, bucket_base);
    bin_write<<<BIN_BLOCKS, 256, 0, stream>>>(src, dst, w, blockbase, bucket_base, tmp_ew, E);
    fine_fill2<<<NBUCK, 256, 0, stream>>>(tmp_ew, bucket_base, csr_ew, row_ptr);

    // ---- Layer 1 ----
    mfma_gemm<256, 128, true><<<gemm_blocks, 256, 0, stream>>>(x, WT1, b1, hA, M);
    pull128_bf<true><<<(M + 3) / 4, 256, 0, stream>>>((const unsigned int*)hA, row_ptr, csr_ew,
                                                      (unsigned int*)hB, M);
    // ---- Layer 2 ----
    mfma_gemm<128, 128, false><<<gemm_blocks, 256, 0, stream>>>(hB, WT2, b2, hA, M);
    pull128_bf<true><<<(M + 3) / 4, 256, 0, stream>>>((const unsigned int*)hA, row_ptr, csr_ew,
                                                      (unsigned int*)hB, M);
    // ---- Layer 3 ----
    mfma_gemm<128, 64, false><<<gemm_blocks, 256, 0, stream>>>(hB, WT3, b3, hA, M);
    pull64_bf<<<(M + 7) / 8, 256, 0, stream>>>((const unsigned int*)hA, row_ptr, csr_ew,
                                               (float2*)d_out, M);
}

// Round 9
// 212.434 us; speedup vs baseline: 1.8935x; 1.0654x over previous
//
#include <hip/hip_runtime.h>
#include <hip/hip_bf16.h>

#define N_NODES 50000
#define BSHIFT  6
#define BSIZE   64
#define NBUCK   ((N_NODES + BSIZE - 1) / BSIZE)   // 782
#define BIN_BLOCKS 256

using short8  = __attribute__((ext_vector_type(8))) short;
using floatx4 = __attribute__((ext_vector_type(4))) float;

__device__ inline short f32_to_bf16_bits(float f) {
    __hip_bfloat16 h = __float2bfloat16(f);
    return *reinterpret_cast<short*>(&h);
}

// ---------------- MFMA GEMM: C_bf16[M,N] = A[M,K] @ W[K,N] + b ----------------
// One 16-row stripe per block; 4 waves each own N/4 cols. No barriers, no loops over stripes.
template<int K, int N, bool A_F32>
__global__ __launch_bounds__(256) void mfma_gemm(const void* __restrict__ Araw,
                                                 const short* __restrict__ WT,
                                                 const float* __restrict__ bias,
                                                 short* __restrict__ C, int M)
{
    constexpr int CW  = N / 4;
    constexpr int TPW = CW / 16;
    constexpr int KS  = K / 32;

    const int tid  = threadIdx.x;
    const int wave = tid >> 6;
    const int lane = tid & 63;
    const int l15  = lane & 15;
    const int lk   = (lane >> 4) * 8;
    const int n0   = wave * CW;

    const int r0 = blockIdx.x * 16;
    if (r0 >= M) return;

    short8 bfrag[TPW][KS];
#pragma unroll
    for (int t = 0; t < TPW; ++t)
#pragma unroll
        for (int ks = 0; ks < KS; ++ks)
            bfrag[t][ks] = *reinterpret_cast<const short8*>(
                &WT[(size_t)(n0 + t * 16 + l15) * K + ks * 32 + lk]);

    float bv[TPW];
#pragma unroll
    for (int t = 0; t < TPW; ++t) bv[t] = bias[n0 + t * 16 + l15];

    const float* Af = (const float*)Araw;
    const short* Ab = (const short*)Araw;

    floatx4 acc[TPW];
#pragma unroll
    for (int t = 0; t < TPW; ++t) acc[t] = (floatx4){0.f, 0.f, 0.f, 0.f};

    const int arow = min(r0 + l15, M - 1);
#pragma unroll
    for (int ks = 0; ks < KS; ++ks) {
        short8 af;
        if (A_F32) {
            const float4 v0 = *reinterpret_cast<const float4*>(&Af[(size_t)arow * K + ks * 32 + lk]);
            const float4 v1 = *reinterpret_cast<const float4*>(&Af[(size_t)arow * K + ks * 32 + lk + 4]);
            af[0] = f32_to_bf16_bits(v0.x); af[1] = f32_to_bf16_bits(v0.y);
            af[2] = f32_to_bf16_bits(v0.z); af[3] = f32_to_bf16_bits(v0.w);
            af[4] = f32_to_bf16_bits(v1.x); af[5] = f32_to_bf16_bits(v1.y);
            af[6] = f32_to_bf16_bits(v1.z); af[7] = f32_to_bf16_bits(v1.w);
        } else {
            af = *reinterpret_cast<const short8*>(&Ab[(size_t)arow * K + ks * 32 + lk]);
        }
#pragma unroll
        for (int t = 0; t < TPW; ++t)
            acc[t] = __builtin_amdgcn_mfma_f32_16x16x32_bf16(af, bfrag[t][ks], acc[t], 0, 0, 0);
    }

    const int rowg = (lane >> 4) * 4;
#pragma unroll
    for (int t = 0; t < TPW; ++t)
#pragma unroll
        for (int j = 0; j < 4; ++j) {
            const int gr = r0 + rowg + j;
            if (gr < M)
                C[(size_t)gr * N + n0 + t * 16 + l15] = f32_to_bf16_bits(acc[t][j] + bv[t]);
        }
}

// ---------------- all three W -> W^T bf16 in one kernel ----------------
__global__ __launch_bounds__(256) void wt_all(const float* __restrict__ W1, short* __restrict__ WT1,
                                              const float* __restrict__ W2, short* __restrict__ WT2,
                                              const float* __restrict__ W3, short* __restrict__ WT3)
{
    const int i = blockIdx.x * 256 + threadIdx.x;
    if (i < 256 * 128) {
        const int k = i >> 7, n = i & 127;
        WT1[(size_t)n * 256 + k] = f32_to_bf16_bits(W1[i]);
    }
    if (i < 128 * 128) {
        const int k = i >> 7, n = i & 127;
        WT2[(size_t)n * 128 + k] = f32_to_bf16_bits(W2[i]);
    }
    if (i < 128 * 64) {
        const int k = i >> 6, n = i & 63;
        WT3[(size_t)n * 128 + k] = f32_to_bf16_bits(W3[i]);
    }
}

// ================= CSR build: block-aggregated counting sort (no global atomics) =================

// Pass A: per-block LDS histogram of dst>>6 over its edge chunk.
__global__ __launch_bounds__(256) void bin_hist(const int* __restrict__ dst,
                                                int* __restrict__ hist_g, int E)
{
    __shared__ int hist[NBUCK];
    for (int t = threadIdx.x; t < NBUCK; t += 256) hist[t] = 0;
    __syncthreads();
    const int chunk = (E + BIN_BLOCKS - 1) / BIN_BLOCKS;
    const int beg = blockIdx.x * chunk;
    const int end = min(beg + chunk, E);
    for (int i = beg + threadIdx.x; i < end; i += 256)
        atomicAdd(&hist[dst[i] >> BSHIFT], 1);
    __syncthreads();
    for (int t = threadIdx.x; t < NBUCK; t += 256)
        hist_g[blockIdx.x * NBUCK + t] = hist[t];
}

// Pass B1: one block per BUCKET; exclusive scan across the BIN_BLOCKS chunks.
__global__ __launch_bounds__(256) void bin_scan_blocks(const int* __restrict__ hist_g,
                                                       int* __restrict__ blockbase,
                                                       int* __restrict__ tot)
{
    __shared__ int s[BIN_BLOCKS];
    const int b = blockIdx.x;
    const int t = threadIdx.x;
    const int v = hist_g[t * NBUCK + b];
    s[t] = v;
    __syncthreads();
#pragma unroll
    for (int off = 1; off < BIN_BLOCKS; off <<= 1) {
        const int tmp = (t >= off) ? s[t - off] : 0;
        __syncthreads();
        s[t] += tmp;
        __syncthreads();
    }
    blockbase[t * NBUCK + b] = s[t] - v;
    if (t == BIN_BLOCKS - 1) tot[b] = s[t];
}

// Pass B2 (1 block): exclusive scan of bucket totals -> bucket_base[0..NBUCK].
__global__ __launch_bounds__(256) void bin_scan_tot(const int* __restrict__ tot,
                                                    int* __restrict__ bucket_base)
{
    __shared__ int psum[256];
    const int t = threadIdx.x;
    int vals[4];
    int s = 0;
#pragma unroll
    for (int j = 0; j < 4; ++j) {
        const int idx = t * 4 + j;
        vals[j] = (idx < NBUCK) ? tot[idx] : 0;
        s += vals[j];
    }
    psum[t] = s;
    __syncthreads();
#pragma unroll
    for (int off = 1; off < 256; off <<= 1) {
        const int tmp = (t >= off) ? psum[t - off] : 0;
        __syncthreads();
        psum[t] += tmp;
        __syncthreads();
    }
    int run = psum[t] - s;
#pragma unroll
    for (int j = 0; j < 4; ++j) {
        const int idx = t * 4 + j;
        if (idx < NBUCK) bucket_base[idx] = run;
        run += vals[j];
    }
    if (t == 255) bucket_base[NBUCK] = run;
}

// Pass C: re-read chunk, LDS cursors, write packed tmp.
// tmp.x = (src << 6) | (dst & 63), tmp.y = w bits.
__global__ __launch_bounds__(256) void bin_write(const int* __restrict__ src,
                                                 const int* __restrict__ dst,
                                                 const float* __restrict__ w,
                                                 const int* __restrict__ blockbase,
                                                 const int* __restrict__ bucket_base,
                                                 int2* __restrict__ tmp, int E)
{
    __shared__ int cur[NBUCK];
    for (int t = threadIdx.x; t < NBUCK; t += 256)
        cur[t] = bucket_base[t] + blockbase[blockIdx.x * NBUCK + t];
    __syncthreads();
    const int chunk = (E + BIN_BLOCKS - 1) / BIN_BLOCKS;
    const int beg = blockIdx.x * chunk;
    const int end = min(beg + chunk, E);
    for (int i = beg + threadIdx.x; i < end; i += 256) {
        const int d = dst[i];
        const int pos = atomicAdd(&cur[d >> BSHIFT], 1);
        tmp[pos] = make_int2((src[i] << BSHIFT) | (d & (BSIZE - 1)), __float_as_int(w[i]));
    }
}

// Pass D: one block per bucket. Emits row_ptr + node-sorted csr_ew.
__global__ __launch_bounds__(256) void fine_fill2(const int2* __restrict__ tmp,
                                                  const int* __restrict__ bucket_base,
                                                  int2* __restrict__ csr_ew,
                                                  int* __restrict__ row_ptr)
{
    __shared__ int hist[BSIZE];
    __shared__ int basel[BSIZE];
    const int b    = blockIdx.x;
    const int t    = threadIdx.x;
    const int rbeg = bucket_base[b];
    const int rend = bucket_base[b + 1];

    if (t < BSIZE) hist[t] = 0;
    __syncthreads();
    for (int i = rbeg + t; i < rend; i += 256)
        atomicAdd(&hist[((unsigned)tmp[i].x) & (BSIZE - 1)], 1);
    __syncthreads();

    if (t < BSIZE) {
        const int v = hist[t];
        int inc = v;
#pragma unroll
        for (int off = 1; off < BSIZE; off <<= 1) {
            const int u = __shfl_up(inc, off, 64);
            if (t >= off) inc += u;
        }
        const int excl = rbeg + inc - v;
        basel[t] = excl;
        const int node = (b << BSHIFT) + t;
        if (node < N_NODES) row_ptr[node] = excl;
        if (b == NBUCK - 1 && t == 0) row_ptr[N_NODES] = bucket_base[NBUCK];
    }
    __syncthreads();

    for (int i = rbeg + t; i < rend; i += 256) {
        const int2 e = tmp[i];
        const unsigned ex = (unsigned)e.x;
        const int pos = atomicAdd(&basel[ex & (BSIZE - 1)], 1);
        csr_ew[pos] = make_int2((int)(ex >> BSHIFT), e.y);
    }
}

// ---------------- pull (bf16 h, D=128): one wave per node ----------------
template<bool RELU>
__global__ __launch_bounds__(256) void pull128_bf(const unsigned int* __restrict__ h,
                                                  const int* __restrict__ row_ptr,
                                                  const int2* __restrict__ csr_ew,
                                                  unsigned int* __restrict__ out, int n_nodes)
{
    const int wave = threadIdx.x >> 6;
    const int lane = threadIdx.x & 63;
    const int node = blockIdx.x * 4 + wave;
    if (node >= n_nodes) return;

    const int beg = row_ptr[node];
    const int end = row_ptr[node + 1];

    float ax0 = 0.f, ay0 = 0.f, ax1 = 0.f, ay1 = 0.f;
    float ax2 = 0.f, ay2 = 0.f, ax3 = 0.f, ay3 = 0.f;

    for (int c = beg; c < end; c += 64) {
        const int idx = c + lane;
        int2 ew = make_int2(0, 0);
        if (idx < end) ew = csr_ew[idx];
        const int cnt = min(64, end - c);

        int j = 0;
        for (; j + 4 <= cnt; j += 4) {
            const int   s0 = __shfl(ew.x, j);
            const int   s1 = __shfl(ew.x, j + 1);
            const int   s2 = __shfl(ew.x, j + 2);
            const int   s3 = __shfl(ew.x, j + 3);
            const float w0 = __int_as_float(__shfl(ew.y, j));
            const float w1 = __int_as_float(__shfl(ew.y, j + 1));
            const float w2 = __int_as_float(__shfl(ew.y, j + 2));
            const float w3 = __int_as_float(__shfl(ew.y, j + 3));
            const unsigned int p0 = h[(size_t)s0 * 64 + lane];
            const unsigned int p1 = h[(size_t)s1 * 64 + lane];
            const unsigned int p2 = h[(size_t)s2 * 64 + lane];
            const unsigned int p3 = h[(size_t)s3 * 64 + lane];
            ax0 = fmaf(__int_as_float(p0 << 16), w0, ax0);
            ay0 = fmaf(__int_as_float(p0 & 0xffff0000u), w0, ay0);
            ax1 = fmaf(__int_as_float(p1 << 16), w1, ax1);
            ay1 = fmaf(__int_as_float(p1 & 0xffff0000u), w1, ay1);
            ax2 = fmaf(__int_as_float(p2 << 16), w2, ax2);
            ay2 = fmaf(__int_as_float(p2 & 0xffff0000u), w2, ay2);
            ax3 = fmaf(__int_as_float(p3 << 16), w3, ax3);
            ay3 = fmaf(__int_as_float(p3 & 0xffff0000u), w3, ay3);
        }
        for (; j < cnt; ++j) {
            const int   s0 = __shfl(ew.x, j);
            const float w0 = __int_as_float(__shfl(ew.y, j));
            const unsigned int p0 = h[(size_t)s0 * 64 + lane];
            ax0 = fmaf(__int_as_float(p0 << 16), w0, ax0);
            ay0 = fmaf(__int_as_float(p0 & 0xffff0000u), w0, ay0);
        }
    }

    float ax = (ax0 + ax1) + (ax2 + ax3);
    float ay = (ay0 + ay1) + (ay2 + ay3);
    if (RELU) { ax = fmaxf(ax, 0.f); ay = fmaxf(ay, 0.f); }
    const unsigned int lo = (unsigned short)f32_to_bf16_bits(ax);
    const unsigned int hi = (unsigned short)f32_to_bf16_bits(ay);
    out[(size_t)node * 64 + lane] = lo | (hi << 16);
}

// ---------------- pull (bf16 h, D=64): two nodes per wave, f32 out ----------------
__global__ __launch_bounds__(256) void pull64_bf(const unsigned int* __restrict__ h,
                                                 const int* __restrict__ row_ptr,
                                                 const int2* __restrict__ csr_ew,
                                                 float2* __restrict__ out, int n_nodes)
{
    const int wave = threadIdx.x >> 6;
    const int lane = threadIdx.x & 63;
    const int half = lane >> 5;
    const int l32  = lane & 31;
    const int node = blockIdx.x * 8 + wave * 2 + half;
    if (node >= n_nodes) return;

    const int beg = row_ptr[node];
    const int end = row_ptr[node + 1];

    float ax0 = 0.f, ay0 = 0.f, ax1 = 0.f, ay1 = 0.f;
    float ax2 = 0.f, ay2 = 0.f, ax3 = 0.f, ay3 = 0.f;

    for (int c = beg; c < end; c += 32) {
        const int idx = c + l32;
        int2 ew = make_int2(0, 0);
        if (idx < end) ew = csr_ew[idx];
        const int cnt = min(32, end - c);

        int j = 0;
        for (; j + 4 <= cnt; j += 4) {
            const int   s0 = __shfl(ew.x, j, 32);
            const int   s1 = __shfl(ew.x, j + 1, 32);
            const int   s2 = __shfl(ew.x, j + 2, 32);
            const int   s3 = __shfl(ew.x, j + 3, 32);
            const float w0 = __int_as_float(__shfl(ew.y, j, 32));
            const float w1 = __int_as_float(__shfl(ew.y, j + 1, 32));
            const float w2 = __int_as_float(__shfl(ew.y, j + 2, 32));
            const float w3 = __int_as_float(__shfl(ew.y, j + 3, 32));
            const unsigned int p0 = h[(size_t)s0 * 32 + l32];
            const unsigned int p1 = h[(size_t)s1 * 32 + l32];
            const unsigned int p2 = h[(size_t)s2 * 32 + l32];
            const unsigned int p3 = h[(size_t)s3 * 32 + l32];
            ax0 = fmaf(__int_as_float(p0 << 16), w0, ax0);
            ay0 = fmaf(__int_as_float(p0 & 0xffff0000u), w0, ay0);
            ax1 = fmaf(__int_as_float(p1 << 16), w1, ax1);
            ay1 = fmaf(__int_as_float(p1 & 0xffff0000u), w1, ay1);
            ax2 = fmaf(__int_as_float(p2 << 16), w2, ax2);
            ay2 = fmaf(__int_as_float(p2 & 0xffff0000u), w2, ay2);
            ax3 = fmaf(__int_as_float(p3 << 16), w3, ax3);
            ay3 = fmaf(__int_as_float(p3 & 0xffff0000u), w3, ay3);
        }
        for (; j < cnt; ++j) {
            const int   s0 = __shfl(ew.x, j, 32);
            const float w0 = __int_as_float(__shfl(ew.y, j, 32));
            const unsigned int p0 = h[(size_t)s0 * 32 + l32];
            ax0 = fmaf(__int_as_float(p0 << 16), w0, ax0);
            ay0 = fmaf(__int_as_float(p0 & 0xffff0000u), w0, ay0);
        }
    }

    const float ax = (ax0 + ax1) + (ax2 + ax3);
    const float ay = (ay0 + ay1) + (ay2 + ay3);
    out[(size_t)node * 32 + l32] = make_float2(ax, ay);
}

extern "C" void kernel_launch(void* const* d_in, const int* in_sizes, int n_in,
                              void* d_out, int out_size, void* d_ws, size_t ws_size,
                              hipStream_t stream)
{
    const float* x   = (const float*)d_in[0];
    const int*   src = (const int*)  d_in[1];
    const int*   dst = (const int*)  d_in[2];
    const float* w   = (const float*)d_in[3];
    const float* W1  = (const float*)d_in[4];
    const float* b1  = (const float*)d_in[5];
    const float* W2  = (const float*)d_in[6];
    const float* b2  = (const float*)d_in[7];
    const float* W3  = (const float*)d_in[8];
    const float* b3  = (const float*)d_in[9];

    const int E = in_sizes[1];
    const int M = N_NODES;

    // workspace layout
    short* hA  = (short*)d_ws;                        // M*128 bf16
    short* hB  = hA + (size_t)M * 128;                // M*128 bf16
    short* WT1 = hB + (size_t)M * 128;                // 128*256
    short* WT2 = WT1 + 128 * 256;                     // 128*128
    short* WT3 = WT2 + 128 * 128;                     // 64*128
    int2*  csr_ew      = (int2*)(WT3 + 64 * 128);     // E pairs
    int2*  tmp_ew      = csr_ew + E;                  // E pairs
    int*   row_ptr     = (int*)(tmp_ew + E);          // 50048
    int*   hist_g      = row_ptr + 50048;             // 256*782 -> pad 200704
    int*   blockbase   = hist_g + 200704;             // 256*782 -> pad 200704
    int*   bucket_base = blockbase + 200704;          // 783 -> pad 1024
    int*   tot         = bucket_base + 1024;          // 782 -> pad 1024

    const int gemm_blocks = (M + 15) / 16;            // 3125

    // ---- weights + CSR build (no global atomics) ----
    wt_all<<<(256 * 128 + 255) / 256, 256, 0, stream>>>(W1, WT1, W2, WT2, W3, WT3);
    bin_hist<<<BIN_BLOCKS, 256, 0, stream>>>(dst, hist_g, E);
    bin_scan_blocks<<<NBUCK, BIN_BLOCKS, 0, stream>>>(hist_g, blockbase, tot);
    bin_scan_tot<<<1, 256, 0, stream>>>(tot, bucket_base);
    bin_write<<<BIN_BLOCKS, 256, 0, stream>>>(src, dst, w, blockbase, bucket_base, tmp_ew, E);
    fine_fill2<<<NBUCK, 256, 0, stream>>>(tmp_ew, bucket_base, csr_ew, row_ptr);

    // ---- Layer 1 ----
    mfma_gemm<256, 128, true><<<gemm_blocks, 256, 0, stream>>>(x, WT1, b1, hA, M);
    pull128_bf<true><<<(M + 3) / 4, 256, 0, stream>>>((const unsigned int*)hA, row_ptr, csr_ew,
                                                      (unsigned int*)hB, M);
    // ---- Layer 2 ----
    mfma_gemm<128, 128, false><<<gemm_blocks, 256, 0, stream>>>(hB, WT2, b2, hA, M);
    pull128_bf<true><<<(M + 3) / 4, 256, 0, stream>>>((const unsigned int*)hA, row_ptr, csr_ew,
                                                      (unsigned int*)hB, M);
    // ---- Layer 3 ----
    mfma_gemm<128, 64, false><<<gemm_blocks, 256, 0, stream>>>(hB, WT3, b3, hA, M);
    pull64_bf<<<(M + 7) / 8, 256, 0, stream>>>((const unsigned int*)hA, row_ptr, csr_ew,
                                               (float2*)d_out, M);
}

// Round 10
// 161.222 us; speedup vs baseline: 2.4950x; 1.3177x over previous
//
#include <hip/hip_runtime.h>
#include <hip/hip_bf16.h>

#define N_NODES 50000
#define BSHIFT  6
#define BSIZE   64
#define NBUCK   ((N_NODES + BSIZE - 1) / BSIZE)   // 782
#define BIN_BLOCKS 256

using short8  = __attribute__((ext_vector_type(8))) short;
using short4v = __attribute__((ext_vector_type(4))) short;
using floatx4 = __attribute__((ext_vector_type(4))) float;

__device__ inline short f32_to_bf16_bits(float f) {
    __hip_bfloat16 h = __float2bfloat16(f);
    return *reinterpret_cast<short*>(&h);
}

// ---------------- MFMA GEMM v3: coalesced loads only ----------------
// Block: 64 rows x N cols. 4 waves = 2 row-groups x 2 col-groups.
// Wave: 32 rows (2 row-tiles) x N/2 cols (CT col-tiles).
// A staged in LDS (coalesced global reads, f32->bf16 fused for layer 1).
// B read from fragment-ordered WTf: each load = contiguous 1KB per wave.
template<int K, int N, bool A_F32>
__global__ __launch_bounds__(256) void mfma_gemm(const void* __restrict__ Araw,
                                                 const short* __restrict__ WTf,
                                                 const float* __restrict__ bias,
                                                 short* __restrict__ C, int M)
{
    constexpr int KS = K / 32;          // K-steps
    constexpr int CT = N / 32;          // col-tiles per wave (4 for N=128, 2 for N=64)
    constexpr int LK = K + 8;           // padded LDS row (stride % 128B rotates banks by 4)

    __shared__ __align__(16) short As[64][LK];

    const int tid  = threadIdx.x;
    const int wave = tid >> 6;
    const int lane = tid & 63;
    const int l15  = lane & 15;
    const int lk   = (lane >> 4) * 8;
    const int wr   = wave >> 1;         // row-group
    const int wc   = wave & 1;          // col-group
    const int r0   = blockIdx.x * 64;

    // ---- stage A (64 rows x K) into LDS, coalesced ----
    if (A_F32) {
        const float* Af = (const float*)Araw;
        // 64 rows * K/4 float4; wave reads one full row per instruction (K=256)
#pragma unroll
        for (int it = 0; it < 64 * (K / 4) / 256; ++it) {
            const int idx = it * 256 + tid;
            const int row = idx / (K / 4);
            const int c4  = idx % (K / 4);
            const int gr  = min(r0 + row, M - 1);
            const float4 v = *reinterpret_cast<const float4*>(&Af[(size_t)gr * K + c4 * 4]);
            short4v s;
            s[0] = f32_to_bf16_bits(v.x); s[1] = f32_to_bf16_bits(v.y);
            s[2] = f32_to_bf16_bits(v.z); s[3] = f32_to_bf16_bits(v.w);
            *reinterpret_cast<short4v*>(&As[row][c4 * 4]) = s;
        }
    } else {
        const short* Ab = (const short*)Araw;
#pragma unroll
        for (int it = 0; it < 64 * (K / 8) / 256; ++it) {
            const int idx = it * 256 + tid;
            const int row = idx / (K / 8);
            const int c8  = idx % (K / 8);
            const int gr  = min(r0 + row, M - 1);
            const short8 v = *reinterpret_cast<const short8*>(&Ab[(size_t)gr * K + c8 * 8]);
            *reinterpret_cast<short8*>(&As[row][c8 * 8]) = v;
        }
    }
    __syncthreads();

    float bv[CT];
#pragma unroll
    for (int t = 0; t < CT; ++t) bv[t] = bias[wc * (N / 2) + t * 16 + l15];

    floatx4 acc[2][CT];
#pragma unroll
    for (int rt = 0; rt < 2; ++rt)
#pragma unroll
        for (int t = 0; t < CT; ++t) acc[rt][t] = (floatx4){0.f, 0.f, 0.f, 0.f};

#pragma unroll
    for (int ks = 0; ks < KS; ++ks) {
        short8 b[CT];
#pragma unroll
        for (int t = 0; t < CT; ++t) {
            const int tg = wc * CT + t;   // global col-tile
            b[t] = *reinterpret_cast<const short8*>(&WTf[((size_t)(tg * KS + ks) * 64 + lane) * 8]);
        }
        short8 a[2];
#pragma unroll
        for (int rt = 0; rt < 2; ++rt)
            a[rt] = *reinterpret_cast<const short8*>(&As[wr * 32 + rt * 16 + l15][ks * 32 + lk]);
#pragma unroll
        for (int rt = 0; rt < 2; ++rt)
#pragma unroll
            for (int t = 0; t < CT; ++t)
                acc[rt][t] = __builtin_amdgcn_mfma_f32_16x16x32_bf16(a[rt], b[t], acc[rt][t], 0, 0, 0);
    }

    const int rowg = (lane >> 4) * 4;
#pragma unroll
    for (int rt = 0; rt < 2; ++rt)
#pragma unroll
        for (int t = 0; t < CT; ++t)
#pragma unroll
            for (int j = 0; j < 4; ++j) {
                const int gr = r0 + wr * 32 + rt * 16 + rowg + j;
                if (gr < M)
                    C[(size_t)gr * N + wc * (N / 2) + t * 16 + l15] =
                        f32_to_bf16_bits(acc[rt][t][j] + bv[t]);
            }
}

// ---------------- W -> fragment-ordered bf16 WTf ----------------
// WTf[((tg*KS + ks)*64 + lane)*8 + e] = W[(ks*32 + (lane>>4)*8 + e) * N + tg*16 + (lane&15)]
__device__ inline void wt_frag(const float* __restrict__ W, short* __restrict__ out,
                               int K, int N, int u)
{
    const int lane = u & 63;
    const int rest = u >> 6;
    const int KS   = K >> 5;
    const int ks   = rest % KS;
    const int tg   = rest / KS;
    const int n    = tg * 16 + (lane & 15);
    const int kb   = ks * 32 + (lane >> 4) * 8;
    short8 s;
#pragma unroll
    for (int e = 0; e < 8; ++e) s[e] = f32_to_bf16_bits(W[(size_t)(kb + e) * N + n]);
    *reinterpret_cast<short8*>(&out[(size_t)u * 8]) = s;
}

__global__ __launch_bounds__(256) void wt_all(const float* __restrict__ W1, short* __restrict__ WT1,
                                              const float* __restrict__ W2, short* __restrict__ WT2,
                                              const float* __restrict__ W3, short* __restrict__ WT3)
{
    const int u = blockIdx.x * 256 + threadIdx.x;
    // sizes: L1 (K=256,N=128): 8*8*64 = 4096; L2: 8*4*64 = 2048; L3: 4*4*64 = 1024
    if (u < 4096)             wt_frag(W1, WT1, 256, 128, u);
    else if (u < 4096 + 2048) wt_frag(W2, WT2, 128, 128, u - 4096);
    else if (u < 7168)        wt_frag(W3, WT3, 128, 64,  u - 6144);
}

// ================= CSR build: block-aggregated counting sort (no global atomics) =================

__global__ __launch_bounds__(256) void bin_hist(const int* __restrict__ dst,
                                                int* __restrict__ hist_g, int E)
{
    __shared__ int hist[NBUCK];
    for (int t = threadIdx.x; t < NBUCK; t += 256) hist[t] = 0;
    __syncthreads();
    const int chunk = (E + BIN_BLOCKS - 1) / BIN_BLOCKS;
    const int beg = blockIdx.x * chunk;
    const int end = min(beg + chunk, E);
    for (int i = beg + threadIdx.x; i < end; i += 256)
        atomicAdd(&hist[dst[i] >> BSHIFT], 1);
    __syncthreads();
    for (int t = threadIdx.x; t < NBUCK; t += 256)
        hist_g[blockIdx.x * NBUCK + t] = hist[t];
}

__global__ __launch_bounds__(256) void bin_scan_blocks(const int* __restrict__ hist_g,
                                                       int* __restrict__ blockbase,
                                                       int* __restrict__ tot)
{
    __shared__ int s[BIN_BLOCKS];
    const int b = blockIdx.x;
    const int t = threadIdx.x;
    const int v = hist_g[t * NBUCK + b];
    s[t] = v;
    __syncthreads();
#pragma unroll
    for (int off = 1; off < BIN_BLOCKS; off <<= 1) {
        const int tmp = (t >= off) ? s[t - off] : 0;
        __syncthreads();
        s[t] += tmp;
        __syncthreads();
    }
    blockbase[t * NBUCK + b] = s[t] - v;
    if (t == BIN_BLOCKS - 1) tot[b] = s[t];
}

__global__ __launch_bounds__(256) void bin_scan_tot(const int* __restrict__ tot,
                                                    int* __restrict__ bucket_base)
{
    __shared__ int psum[256];
    const int t = threadIdx.x;
    int vals[4];
    int s = 0;
#pragma unroll
    for (int j = 0; j < 4; ++j) {
        const int idx = t * 4 + j;
        vals[j] = (idx < NBUCK) ? tot[idx] : 0;
        s += vals[j];
    }
    psum[t] = s;
    __syncthreads();
#pragma unroll
    for (int off = 1; off < 256; off <<= 1) {
        const int tmp = (t >= off) ? psum[t - off] : 0;
        __syncthreads();
        psum[t] += tmp;
        __syncthreads();
    }
    int run = psum[t] - s;
#pragma unroll
    for (int j = 0; j < 4; ++j) {
        const int idx = t * 4 + j;
        if (idx < NBUCK) bucket_base[idx] = run;
        run += vals[j];
    }
    if (t == 255) bucket_base[NBUCK] = run;
}

__global__ __launch_bounds__(256) void bin_write(const int* __restrict__ src,
                                                 const int* __restrict__ dst,
                                                 const float* __restrict__ w,
                                                 const int* __restrict__ blockbase,
                                                 const int* __restrict__ bucket_base,
                                                 int2* __restrict__ tmp, int E)
{
    __shared__ int cur[NBUCK];
    for (int t = threadIdx.x; t < NBUCK; t += 256)
        cur[t] = bucket_base[t] + blockbase[blockIdx.x * NBUCK + t];
    __syncthreads();
    const int chunk = (E + BIN_BLOCKS - 1) / BIN_BLOCKS;
    const int beg = blockIdx.x * chunk;
    const int end = min(beg + chunk, E);
    for (int i = beg + threadIdx.x; i < end; i += 256) {
        const int d = dst[i];
        const int pos = atomicAdd(&cur[d >> BSHIFT], 1);
        tmp[pos] = make_int2((src[i] << BSHIFT) | (d & (BSIZE - 1)), __float_as_int(w[i]));
    }
}

__global__ __launch_bounds__(256) void fine_fill2(const int2* __restrict__ tmp,
                                                  const int* __restrict__ bucket_base,
                                                  int2* __restrict__ csr_ew,
                                                  int* __restrict__ row_ptr)
{
    __shared__ int hist[BSIZE];
    __shared__ int basel[BSIZE];
    const int b    = blockIdx.x;
    const int t    = threadIdx.x;
    const int rbeg = bucket_base[b];
    const int rend = bucket_base[b + 1];

    if (t < BSIZE) hist[t] = 0;
    __syncthreads();
    for (int i = rbeg + t; i < rend; i += 256)
        atomicAdd(&hist[((unsigned)tmp[i].x) & (BSIZE - 1)], 1);
    __syncthreads();

    if (t < BSIZE) {
        const int v = hist[t];
        int inc = v;
#pragma unroll
        for (int off = 1; off < BSIZE; off <<= 1) {
            const int u = __shfl_up(inc, off, 64);
            if (t >= off) inc += u;
        }
        const int excl = rbeg + inc - v;
        basel[t] = excl;
        const int node = (b << BSHIFT) + t;
        if (node < N_NODES) row_ptr[node] = excl;
        if (b == NBUCK - 1 && t == 0) row_ptr[N_NODES] = bucket_base[NBUCK];
    }
    __syncthreads();

    for (int i = rbeg + t; i < rend; i += 256) {
        const int2 e = tmp[i];
        const unsigned ex = (unsigned)e.x;
        const int pos = atomicAdd(&basel[ex & (BSIZE - 1)], 1);
        csr_ew[pos] = make_int2((int)(ex >> BSHIFT), e.y);
    }
}

// ---------------- pull (bf16 h, D=128): one wave per node ----------------
template<bool RELU>
__global__ __launch_bounds__(256) void pull128_bf(const unsigned int* __restrict__ h,
                                                  const int* __restrict__ row_ptr,
                                                  const int2* __restrict__ csr_ew,
                                                  unsigned int* __restrict__ out, int n_nodes)
{
    const int wave = threadIdx.x >> 6;
    const int lane = threadIdx.x & 63;
    const int node = blockIdx.x * 4 + wave;
    if (node >= n_nodes) return;

    const int beg = row_ptr[node];
    const int end = row_ptr[node + 1];

    float ax0 = 0.f, ay0 = 0.f, ax1 = 0.f, ay1 = 0.f;
    float ax2 = 0.f, ay2 = 0.f, ax3 = 0.f, ay3 = 0.f;

    for (int c = beg; c < end; c += 64) {
        const int idx = c + lane;
        int2 ew = make_int2(0, 0);
        if (idx < end) ew = csr_ew[idx];
        const int cnt = min(64, end - c);

        int j = 0;
        for (; j + 4 <= cnt; j += 4) {
            const int   s0 = __shfl(ew.x, j);
            const int   s1 = __shfl(ew.x, j + 1);
            const int   s2 = __shfl(ew.x, j + 2);
            const int   s3 = __shfl(ew.x, j + 3);
            const float w0 = __int_as_float(__shfl(ew.y, j));
            const float w1 = __int_as_float(__shfl(ew.y, j + 1));
            const float w2 = __int_as_float(__shfl(ew.y, j + 2));
            const float w3 = __int_as_float(__shfl(ew.y, j + 3));
            const unsigned int p0 = h[(size_t)s0 * 64 + lane];
            const unsigned int p1 = h[(size_t)s1 * 64 + lane];
            const unsigned int p2 = h[(size_t)s2 * 64 + lane];
            const unsigned int p3 = h[(size_t)s3 * 64 + lane];
            ax0 = fmaf(__int_as_float(p0 << 16), w0, ax0);
            ay0 = fmaf(__int_as_float(p0 & 0xffff0000u), w0, ay0);
            ax1 = fmaf(__int_as_float(p1 << 16), w1, ax1);
            ay1 = fmaf(__int_as_float(p1 & 0xffff0000u), w1, ay1);
            ax2 = fmaf(__int_as_float(p2 << 16), w2, ax2);
            ay2 = fmaf(__int_as_float(p2 & 0xffff0000u), w2, ay2);
            ax3 = fmaf(__int_as_float(p3 << 16), w3, ax3);
            ay3 = fmaf(__int_as_float(p3 & 0xffff0000u), w3, ay3);
        }
        for (; j < cnt; ++j) {
            const int   s0 = __shfl(ew.x, j);
            const float w0 = __int_as_float(__shfl(ew.y, j));
            const unsigned int p0 = h[(size_t)s0 * 64 + lane];
            ax0 = fmaf(__int_as_float(p0 << 16), w0, ax0);
            ay0 = fmaf(__int_as_float(p0 & 0xffff0000u), w0, ay0);
        }
    }

    float ax = (ax0 + ax1) + (ax2 + ax3);
    float ay = (ay0 + ay1) + (ay2 + ay3);
    if (RELU) { ax = fmaxf(ax, 0.f); ay = fmaxf(ay, 0.f); }
    const unsigned int lo = (unsigned short)f32_to_bf16_bits(ax);
    const unsigned int hi = (unsigned short)f32_to_bf16_bits(ay);
    out[(size_t)node * 64 + lane] = lo | (hi << 16);
}

// ---------------- pull (bf16 h, D=64): two nodes per wave, f32 out ----------------
__global__ __launch_bounds__(256) void pull64_bf(const unsigned int* __restrict__ h,
                                                 const int* __restrict__ row_ptr,
                                                 const int2* __restrict__ csr_ew,
                                                 float2* __restrict__ out, int n_nodes)
{
    const int wave = threadIdx.x >> 6;
    const int lane = threadIdx.x & 63;
    const int half = lane >> 5;
    const int l32  = lane & 31;
    const int node = blockIdx.x * 8 + wave * 2 + half;
    if (node >= n_nodes) return;

    const int beg = row_ptr[node];
    const int end = row_ptr[node + 1];

    float ax0 = 0.f, ay0 = 0.f, ax1 = 0.f, ay1 = 0.f;
    float ax2 = 0.f, ay2 = 0.f, ax3 = 0.f, ay3 = 0.f;

    for (int c = beg; c < end; c += 32) {
        const int idx = c + l32;
        int2 ew = make_int2(0, 0);
        if (idx < end) ew = csr_ew[idx];
        const int cnt = min(32, end - c);

        int j = 0;
        for (; j + 4 <= cnt; j += 4) {
            const int   s0 = __shfl(ew.x, j, 32);
            const int   s1 = __shfl(ew.x, j + 1, 32);
            const int   s2 = __shfl(ew.x, j + 2, 32);
            const int   s3 = __shfl(ew.x, j + 3, 32);
            const float w0 = __int_as_float(__shfl(ew.y, j, 32));
            const float w1 = __int_as_float(__shfl(ew.y, j + 1, 32));
            const float w2 = __int_as_float(__shfl(ew.y, j + 2, 32));
            const float w3 = __int_as_float(__shfl(ew.y, j + 3, 32));
            const unsigned int p0 = h[(size_t)s0 * 32 + l32];
            const unsigned int p1 = h[(size_t)s1 * 32 + l32];
            const unsigned int p2 = h[(size_t)s2 * 32 + l32];
            const unsigned int p3 = h[(size_t)s3 * 32 + l32];
            ax0 = fmaf(__int_as_float(p0 << 16), w0, ax0);
            ay0 = fmaf(__int_as_float(p0 & 0xffff0000u), w0, ay0);
            ax1 = fmaf(__int_as_float(p1 << 16), w1, ax1);
            ay1 = fmaf(__int_as_float(p1 & 0xffff0000u), w1, ay1);
            ax2 = fmaf(__int_as_float(p2 << 16), w2, ax2);
            ay2 = fmaf(__int_as_float(p2 & 0xffff0000u), w2, ay2);
            ax3 = fmaf(__int_as_float(p3 << 16), w3, ax3);
            ay3 = fmaf(__int_as_float(p3 & 0xffff0000u), w3, ay3);
        }
        for (; j < cnt; ++j) {
            const int   s0 = __shfl(ew.x, j, 32);
            const float w0 = __int_as_float(__shfl(ew.y, j, 32));
            const unsigned int p0 = h[(size_t)s0 * 32 + l32];
            ax0 = fmaf(__int_as_float(p0 << 16), w0, ax0);
            ay0 = fmaf(__int_as_float(p0 & 0xffff0000u), w0, ay0);
        }
    }

    const float ax = (ax0 + ax1) + (ax2 + ax3);
    const float ay = (ay0 + ay1) + (ay2 + ay3);
    out[(size_t)node * 32 + l32] = make_float2(ax, ay);
}

extern "C" void kernel_launch(void* const* d_in, const int* in_sizes, int n_in,
                              void* d_out, int out_size, void* d_ws, size_t ws_size,
                              hipStream_t stream)
{
    const float* x   = (const float*)d_in[0];
    const int*   src = (const int*)  d_in[1];
    const int*   dst = (const int*)  d_in[2];
    const float* w   = (const float*)d_in[3];
    const float* W1  = (const float*)d_in[4];
    const float* b1  = (const float*)d_in[5];
    const float* W2  = (const float*)d_in[6];
    const float* b2  = (const float*)d_in[7];
    const float* W3  = (const float*)d_in[8];
    const float* b3  = (const float*)d_in[9];

    const int E = in_sizes[1];
    const int M = N_NODES;

    // workspace layout
    short* hA  = (short*)d_ws;                        // M*128 bf16
    short* hB  = hA + (size_t)M * 128;                // M*128 bf16
    short* WT1 = hB + (size_t)M * 128;                // 128*256 (frag-ordered)
    short* WT2 = WT1 + 128 * 256;                     // 128*128
    short* WT3 = WT2 + 128 * 128;                     // 64*128
    int2*  csr_ew      = (int2*)(WT3 + 64 * 128);     // E pairs
    int2*  tmp_ew      = csr_ew + E;                  // E pairs
    int*   row_ptr     = (int*)(tmp_ew + E);          // 50048
    int*   hist_g      = row_ptr + 50048;             // 256*782 -> pad 200704
    int*   blockbase   = hist_g + 200704;             // 256*782 -> pad 200704
    int*   bucket_base = blockbase + 200704;          // 783 -> pad 1024
    int*   tot         = bucket_base + 1024;          // 782 -> pad 1024

    const int gemm_blocks = (M + 63) / 64;            // 782

    // ---- weights + CSR build (no global atomics) ----
    wt_all<<<28, 256, 0, stream>>>(W1, WT1, W2, WT2, W3, WT3);
    bin_hist<<<BIN_BLOCKS, 256, 0, stream>>>(dst, hist_g, E);
    bin_scan_blocks<<<NBUCK, BIN_BLOCKS, 0, stream>>>(hist_g, blockbase, tot);
    bin_scan_tot<<<1, 256, 0, stream>>>(tot, bucket_base);
    bin_write<<<BIN_BLOCKS, 256, 0, stream>>>(src, dst, w, blockbase, bucket_base, tmp_ew, E);
    fine_fill2<<<NBUCK, 256, 0, stream>>>(tmp_ew, bucket_base, csr_ew, row_ptr);

    // ---- Layer 1 ----
    mfma_gemm<256, 128, true><<<gemm_blocks, 256, 0, stream>>>(x, WT1, b1, hA, M);
    pull128_bf<true><<<(M + 3) / 4, 256, 0, stream>>>((const unsigned int*)hA, row_ptr, csr_ew,
                                                      (unsigned int*)hB, M);
    // ---- Layer 2 ----
    mfma_gemm<128, 128, false><<<gemm_blocks, 256, 0, stream>>>(hB, WT2, b2, hA, M);
    pull128_bf<true><<<(M + 3) / 4, 256, 0, stream>>>((const unsigned int*)hA, row_ptr, csr_ew,
                                                      (unsigned int*)hB, M);
    // ---- Layer 3 ----
    mfma_gemm<128, 64, false><<<gemm_blocks, 256, 0, stream>>>(hB, WT3, b3, hA, M);
    pull64_bf<<<(M + 7) / 8, 256, 0, stream>>>((const unsigned int*)hA, row_ptr, csr_ew,
                                               (float2*)d_out, M);
}

// Round 11
// 153.265 us; speedup vs baseline: 2.6245x; 1.0519x over previous
//
#include <hip/hip_runtime.h>
#include <hip/hip_bf16.h>

#define N_NODES 50000
#define BSHIFT  6
#define BSIZE   64
#define NBUCK   ((N_NODES + BSIZE - 1) / BSIZE)   // 782
#define BIN_BLOCKS 256

using short8  = __attribute__((ext_vector_type(8))) short;
using short4v = __attribute__((ext_vector_type(4))) short;
using floatx4 = __attribute__((ext_vector_type(4))) float;

__device__ inline short f32_to_bf16_bits(float f) {
    __hip_bfloat16 h = __float2bfloat16(f);
    return *reinterpret_cast<short*>(&h);
}

// ---------------- MFMA GEMM v3: coalesced loads only ----------------
template<int K, int N, bool A_F32>
__global__ __launch_bounds__(256) void mfma_gemm(const void* __restrict__ Araw,
                                                 const short* __restrict__ WTf,
                                                 const float* __restrict__ bias,
                                                 short* __restrict__ C, int M)
{
    constexpr int KS = K / 32;
    constexpr int CT = N / 32;
    constexpr int LK = K + 8;

    __shared__ __align__(16) short As[64][LK];

    const int tid  = threadIdx.x;
    const int wave = tid >> 6;
    const int lane = tid & 63;
    const int l15  = lane & 15;
    const int lk   = (lane >> 4) * 8;
    const int wr   = wave >> 1;
    const int wc   = wave & 1;
    const int r0   = blockIdx.x * 64;

    if (A_F32) {
        const float* Af = (const float*)Araw;
#pragma unroll
        for (int it = 0; it < 64 * (K / 4) / 256; ++it) {
            const int idx = it * 256 + tid;
            const int row = idx / (K / 4);
            const int c4  = idx % (K / 4);
            const int gr  = min(r0 + row, M - 1);
            const float4 v = *reinterpret_cast<const float4*>(&Af[(size_t)gr * K + c4 * 4]);
            short4v s;
            s[0] = f32_to_bf16_bits(v.x); s[1] = f32_to_bf16_bits(v.y);
            s[2] = f32_to_bf16_bits(v.z); s[3] = f32_to_bf16_bits(v.w);
            *reinterpret_cast<short4v*>(&As[row][c4 * 4]) = s;
        }
    } else {
        const short* Ab = (const short*)Araw;
#pragma unroll
        for (int it = 0; it < 64 * (K / 8) / 256; ++it) {
            const int idx = it * 256 + tid;
            const int row = idx / (K / 8);
            const int c8  = idx % (K / 8);
            const int gr  = min(r0 + row, M - 1);
            const short8 v = *reinterpret_cast<const short8*>(&Ab[(size_t)gr * K + c8 * 8]);
            *reinterpret_cast<short8*>(&As[row][c8 * 8]) = v;
        }
    }
    __syncthreads();

    float bv[CT];
#pragma unroll
    for (int t = 0; t < CT; ++t) bv[t] = bias[wc * (N / 2) + t * 16 + l15];

    floatx4 acc[2][CT];
#pragma unroll
    for (int rt = 0; rt < 2; ++rt)
#pragma unroll
        for (int t = 0; t < CT; ++t) acc[rt][t] = (floatx4){0.f, 0.f, 0.f, 0.f};

#pragma unroll
    for (int ks = 0; ks < KS; ++ks) {
        short8 b[CT];
#pragma unroll
        for (int t = 0; t < CT; ++t) {
            const int tg = wc * CT + t;
            b[t] = *reinterpret_cast<const short8*>(&WTf[((size_t)(tg * KS + ks) * 64 + lane) * 8]);
        }
        short8 a[2];
#pragma unroll
        for (int rt = 0; rt < 2; ++rt)
            a[rt] = *reinterpret_cast<const short8*>(&As[wr * 32 + rt * 16 + l15][ks * 32 + lk]);
#pragma unroll
        for (int rt = 0; rt < 2; ++rt)
#pragma unroll
            for (int t = 0; t < CT; ++t)
                acc[rt][t] = __builtin_amdgcn_mfma_f32_16x16x32_bf16(a[rt], b[t], acc[rt][t], 0, 0, 0);
    }

    const int rowg = (lane >> 4) * 4;
#pragma unroll
    for (int rt = 0; rt < 2; ++rt)
#pragma unroll
        for (int t = 0; t < CT; ++t)
#pragma unroll
            for (int j = 0; j < 4; ++j) {
                const int gr = r0 + wr * 32 + rt * 16 + rowg + j;
                if (gr < M)
                    C[(size_t)gr * N + wc * (N / 2) + t * 16 + l15] =
                        f32_to_bf16_bits(acc[rt][t][j] + bv[t]);
            }
}

// ---------------- W -> fragment-ordered bf16 WTf ----------------
__device__ inline void wt_frag(const float* __restrict__ W, short* __restrict__ out,
                               int K, int N, int u)
{
    const int lane = u & 63;
    const int rest = u >> 6;
    const int KS   = K >> 5;
    const int ks   = rest % KS;
    const int tg   = rest / KS;
    const int n    = tg * 16 + (lane & 15);
    const int kb   = ks * 32 + (lane >> 4) * 8;
    short8 s;
#pragma unroll
    for (int e = 0; e < 8; ++e) s[e] = f32_to_bf16_bits(W[(size_t)(kb + e) * N + n]);
    *reinterpret_cast<short8*>(&out[(size_t)u * 8]) = s;
}

__global__ __launch_bounds__(256) void wt_all(const float* __restrict__ W1, short* __restrict__ WT1,
                                              const float* __restrict__ W2, short* __restrict__ WT2,
                                              const float* __restrict__ W3, short* __restrict__ WT3)
{
    const int u = blockIdx.x * 256 + threadIdx.x;
    if (u < 4096)             wt_frag(W1, WT1, 256, 128, u);
    else if (u < 4096 + 2048) wt_frag(W2, WT2, 128, 128, u - 4096);
    else if (u < 7168)        wt_frag(W3, WT3, 128, 64,  u - 6144);
}

// ================= CSR build: block-aggregated counting sort (no global atomics) =================

__global__ __launch_bounds__(256) void bin_hist(const int* __restrict__ dst,
                                                int* __restrict__ hist_g, int E)
{
    __shared__ int hist[NBUCK];
    for (int t = threadIdx.x; t < NBUCK; t += 256) hist[t] = 0;
    __syncthreads();
    const int chunk = (E + BIN_BLOCKS - 1) / BIN_BLOCKS;
    const int beg = blockIdx.x * chunk;
    const int end = min(beg + chunk, E);
    for (int i = beg + threadIdx.x; i < end; i += 256)
        atomicAdd(&hist[dst[i] >> BSHIFT], 1);
    __syncthreads();
    for (int t = threadIdx.x; t < NBUCK; t += 256)
        hist_g[blockIdx.x * NBUCK + t] = hist[t];
}

__global__ __launch_bounds__(256) void bin_scan_blocks(const int* __restrict__ hist_g,
                                                       int* __restrict__ blockbase,
                                                       int* __restrict__ tot)
{
    __shared__ int s[BIN_BLOCKS];
    const int b = blockIdx.x;
    const int t = threadIdx.x;
    const int v = hist_g[t * NBUCK + b];
    s[t] = v;
    __syncthreads();
#pragma unroll
    for (int off = 1; off < BIN_BLOCKS; off <<= 1) {
        const int tmp = (t >= off) ? s[t - off] : 0;
        __syncthreads();
        s[t] += tmp;
        __syncthreads();
    }
    blockbase[t * NBUCK + b] = s[t] - v;
    if (t == BIN_BLOCKS - 1) tot[b] = s[t];
}

__global__ __launch_bounds__(256) void bin_scan_tot(const int* __restrict__ tot,
                                                    int* __restrict__ bucket_base)
{
    __shared__ int psum[256];
    const int t = threadIdx.x;
    int vals[4];
    int s = 0;
#pragma unroll
    for (int j = 0; j < 4; ++j) {
        const int idx = t * 4 + j;
        vals[j] = (idx < NBUCK) ? tot[idx] : 0;
        s += vals[j];
    }
    psum[t] = s;
    __syncthreads();
#pragma unroll
    for (int off = 1; off < 256; off <<= 1) {
        const int tmp = (t >= off) ? psum[t - off] : 0;
        __syncthreads();
        psum[t] += tmp;
        __syncthreads();
    }
    int run = psum[t] - s;
#pragma unroll
    for (int j = 0; j < 4; ++j) {
        const int idx = t * 4 + j;
        if (idx < NBUCK) bucket_base[idx] = run;
        run += vals[j];
    }
    if (t == 255) bucket_base[NBUCK] = run;
}

__global__ __launch_bounds__(256) void bin_write(const int* __restrict__ src,
                                                 const int* __restrict__ dst,
                                                 const float* __restrict__ w,
                                                 const int* __restrict__ blockbase,
                                                 const int* __restrict__ bucket_base,
                                                 int2* __restrict__ tmp, int E)
{
    __shared__ int cur[NBUCK];
    for (int t = threadIdx.x; t < NBUCK; t += 256)
        cur[t] = bucket_base[t] + blockbase[blockIdx.x * NBUCK + t];
    __syncthreads();
    const int chunk = (E + BIN_BLOCKS - 1) / BIN_BLOCKS;
    const int beg = blockIdx.x * chunk;
    const int end = min(beg + chunk, E);
    for (int i = beg + threadIdx.x; i < end; i += 256) {
        const int d = dst[i];
        const int pos = atomicAdd(&cur[d >> BSHIFT], 1);
        tmp[pos] = make_int2((src[i] << BSHIFT) | (d & (BSIZE - 1)), __float_as_int(w[i]));
    }
}

// Pass D: one block per bucket. Emits row_ptr + node-sorted packed 4B csr entries:
// entry = (src << 16) | bf16(w)
__global__ __launch_bounds__(256) void fine_fill2(const int2* __restrict__ tmp,
                                                  const int* __restrict__ bucket_base,
                                                  unsigned int* __restrict__ csr_ew,
                                                  int* __restrict__ row_ptr)
{
    __shared__ int hist[BSIZE];
    __shared__ int basel[BSIZE];
    const int b    = blockIdx.x;
    const int t    = threadIdx.x;
    const int rbeg = bucket_base[b];
    const int rend = bucket_base[b + 1];

    if (t < BSIZE) hist[t] = 0;
    __syncthreads();
    for (int i = rbeg + t; i < rend; i += 256)
        atomicAdd(&hist[((unsigned)tmp[i].x) & (BSIZE - 1)], 1);
    __syncthreads();

    if (t < BSIZE) {
        const int v = hist[t];
        int inc = v;
#pragma unroll
        for (int off = 1; off < BSIZE; off <<= 1) {
            const int u = __shfl_up(inc, off, 64);
            if (t >= off) inc += u;
        }
        const int excl = rbeg + inc - v;
        basel[t] = excl;
        const int node = (b << BSHIFT) + t;
        if (node < N_NODES) row_ptr[node] = excl;
        if (b == NBUCK - 1 && t == 0) row_ptr[N_NODES] = bucket_base[NBUCK];
    }
    __syncthreads();

    for (int i = rbeg + t; i < rend; i += 256) {
        const int2 e = tmp[i];
        const unsigned ex = (unsigned)e.x;
        const int pos = atomicAdd(&basel[ex & (BSIZE - 1)], 1);
        const unsigned wb = (unsigned short)f32_to_bf16_bits(__int_as_float(e.y));
        csr_ew[pos] = ((ex >> BSHIFT) << 16) | wb;
    }
}

// ---------------- pull (bf16 h, D=128): one wave per node, 8-deep masked rounds ----------------
template<bool RELU>
__global__ __launch_bounds__(256) void pull128_bf(const unsigned int* __restrict__ h,
                                                  const int* __restrict__ row_ptr,
                                                  const unsigned int* __restrict__ csr_ew,
                                                  unsigned int* __restrict__ out, int n_nodes)
{
    const int wave = threadIdx.x >> 6;
    const int lane = threadIdx.x & 63;
    const int node = blockIdx.x * 4 + wave;
    if (node >= n_nodes) return;

    const int beg = row_ptr[node];
    const int end = row_ptr[node + 1];

    float ax[8], ay[8];
#pragma unroll
    for (int u = 0; u < 8; ++u) { ax[u] = 0.f; ay[u] = 0.f; }

    for (int c = beg; c < end; c += 64) {
        const int idx = c + lane;
        const unsigned ew = (idx < end) ? csr_ew[idx] : 0u;
        const int cnt = min(64, end - c);

        for (int j = 0; j < cnt; j += 8) {
            unsigned e[8];
#pragma unroll
            for (int u = 0; u < 8; ++u) {
                const unsigned v = __shfl(ew, j + u);
                e[u] = (j + u < cnt) ? v : 0u;        // pad: src=0, w=+0.0
            }
            unsigned p[8];
#pragma unroll
            for (int u = 0; u < 8; ++u)
                p[u] = h[(size_t)(e[u] >> 16) * 64 + lane];
#pragma unroll
            for (int u = 0; u < 8; ++u) {
                const float wv = __int_as_float(e[u] << 16);
                ax[u] = fmaf(__int_as_float(p[u] << 16), wv, ax[u]);
                ay[u] = fmaf(__int_as_float(p[u] & 0xffff0000u), wv, ay[u]);
            }
        }
    }

    float axs = ((ax[0] + ax[1]) + (ax[2] + ax[3])) + ((ax[4] + ax[5]) + (ax[6] + ax[7]));
    float ays = ((ay[0] + ay[1]) + (ay[2] + ay[3])) + ((ay[4] + ay[5]) + (ay[6] + ay[7]));
    if (RELU) { axs = fmaxf(axs, 0.f); ays = fmaxf(ays, 0.f); }
    const unsigned lo = (unsigned short)f32_to_bf16_bits(axs);
    const unsigned hi = (unsigned short)f32_to_bf16_bits(ays);
    out[(size_t)node * 64 + lane] = lo | (hi << 16);
}

// ---------------- pull (bf16 h, D=64): two nodes per wave, f32 out ----------------
__global__ __launch_bounds__(256) void pull64_bf(const unsigned int* __restrict__ h,
                                                 const int* __restrict__ row_ptr,
                                                 const unsigned int* __restrict__ csr_ew,
                                                 float2* __restrict__ out, int n_nodes)
{
    const int wave = threadIdx.x >> 6;
    const int lane = threadIdx.x & 63;
    const int half = lane >> 5;
    const int l32  = lane & 31;
    const int node = blockIdx.x * 8 + wave * 2 + half;
    if (node >= n_nodes) return;

    const int beg = row_ptr[node];
    const int end = row_ptr[node + 1];

    float ax[8], ay[8];
#pragma unroll
    for (int u = 0; u < 8; ++u) { ax[u] = 0.f; ay[u] = 0.f; }

    for (int c = beg; c < end; c += 32) {
        const int idx = c + l32;
        const unsigned ew = (idx < end) ? csr_ew[idx] : 0u;
        const int cnt = min(32, end - c);

        for (int j = 0; j < cnt; j += 8) {
            unsigned e[8];
#pragma unroll
            for (int u = 0; u < 8; ++u) {
                const unsigned v = __shfl(ew, j + u, 32);
                e[u] = (j + u < cnt) ? v : 0u;
            }
            unsigned p[8];
#pragma unroll
            for (int u = 0; u < 8; ++u)
                p[u] = h[(size_t)(e[u] >> 16) * 32 + l32];
#pragma unroll
            for (int u = 0; u < 8; ++u) {
                const float wv = __int_as_float(e[u] << 16);
                ax[u] = fmaf(__int_as_float(p[u] << 16), wv, ax[u]);
                ay[u] = fmaf(__int_as_float(p[u] & 0xffff0000u), wv, ay[u]);
            }
        }
    }

    const float axs = ((ax[0] + ax[1]) + (ax[2] + ax[3])) + ((ax[4] + ax[5]) + (ax[6] + ax[7]));
    const float ays = ((ay[0] + ay[1]) + (ay[2] + ay[3])) + ((ay[4] + ay[5]) + (ay[6] + ay[7]));
    out[(size_t)node * 32 + l32] = make_float2(axs, ays);
}

extern "C" void kernel_launch(void* const* d_in, const int* in_sizes, int n_in,
                              void* d_out, int out_size, void* d_ws, size_t ws_size,
                              hipStream_t stream)
{
    const float* x   = (const float*)d_in[0];
    const int*   src = (const int*)  d_in[1];
    const int*   dst = (const int*)  d_in[2];
    const float* w   = (const float*)d_in[3];
    const float* W1  = (const float*)d_in[4];
    const float* b1  = (const float*)d_in[5];
    const float* W2  = (const float*)d_in[6];
    const float* b2  = (const float*)d_in[7];
    const float* W3  = (const float*)d_in[8];
    const float* b3  = (const float*)d_in[9];

    const int E = in_sizes[1];
    const int M = N_NODES;

    // workspace layout
    short* hA  = (short*)d_ws;                        // M*128 bf16
    short* hB  = hA + (size_t)M * 128;                // M*128 bf16
    short* WT1 = hB + (size_t)M * 128;                // 128*256 (frag-ordered)
    short* WT2 = WT1 + 128 * 256;                     // 128*128
    short* WT3 = WT2 + 128 * 128;                     // 64*128
    unsigned int* csr_ew = (unsigned int*)(WT3 + 64 * 128);  // E u32
    int2*  tmp_ew      = (int2*)(csr_ew + ((E + 1) & ~1));   // E pairs (8B-aligned)
    int*   row_ptr     = (int*)(tmp_ew + E);          // 50048
    int*   hist_g      = row_ptr + 50048;             // 256*782 -> pad 200704
    int*   blockbase   = hist_g + 200704;             // 256*782 -> pad 200704
    int*   bucket_base = blockbase + 200704;          // 783 -> pad 1024
    int*   tot         = bucket_base + 1024;          // 782 -> pad 1024

    const int gemm_blocks = (M + 63) / 64;            // 782

    // ---- weights + CSR build (no global atomics) ----
    wt_all<<<28, 256, 0, stream>>>(W1, WT1, W2, WT2, W3, WT3);
    bin_hist<<<BIN_BLOCKS, 256, 0, stream>>>(dst, hist_g, E);
    bin_scan_blocks<<<NBUCK, BIN_BLOCKS, 0, stream>>>(hist_g, blockbase, tot);
    bin_scan_tot<<<1, 256, 0, stream>>>(tot, bucket_base);
    bin_write<<<BIN_BLOCKS, 256, 0, stream>>>(src, dst, w, blockbase, bucket_base, tmp_ew, E);
    fine_fill2<<<NBUCK, 256, 0, stream>>>(tmp_ew, bucket_base, csr_ew, row_ptr);

    // ---- Layer 1 ----
    mfma_gemm<256, 128, true><<<gemm_blocks, 256, 0, stream>>>(x, WT1, b1, hA, M);
    pull128_bf<true><<<(M + 3) / 4, 256, 0, stream>>>((const unsigned int*)hA, row_ptr, csr_ew,
                                                      (unsigned int*)hB, M);
    // ---- Layer 2 ----
    mfma_gemm<128, 128, false><<<gemm_blocks, 256, 0, stream>>>(hB, WT2, b2, hA, M);
    pull128_bf<true><<<(M + 3) / 4, 256, 0, stream>>>((const unsigned int*)hA, row_ptr, csr_ew,
                                                      (unsigned int*)hB, M);
    // ---- Layer 3 ----
    mfma_gemm<128, 64, false><<<gemm_blocks, 256, 0, stream>>>(hB, WT3, b3, hA, M);
    pull64_bf<<<(M + 7) / 8, 256, 0, stream>>>((const unsigned int*)hA, row_ptr, csr_ew,
                                               (float2*)d_out, M);
}

// Round 12
// 147.560 us; speedup vs baseline: 2.7259x; 1.0387x over previous
//
#include <hip/hip_runtime.h>
#include <hip/hip_bf16.h>

#define N_NODES 50000
#define BSHIFT  6
#define BSIZE   64
#define NBUCK   ((N_NODES + BSIZE - 1) / BSIZE)   // 782
#define BIN_BLOCKS 256

using short8  = __attribute__((ext_vector_type(8))) short;
using short4v = __attribute__((ext_vector_type(4))) short;
using floatx4 = __attribute__((ext_vector_type(4))) float;

__device__ inline short f32_to_bf16_bits(float f) {
    __hip_bfloat16 h = __float2bfloat16(f);
    return *reinterpret_cast<short*>(&h);
}

// ---------------- MFMA GEMM (layer 1 only): coalesced loads ----------------
template<int K, int N, bool A_F32>
__global__ __launch_bounds__(256) void mfma_gemm(const void* __restrict__ Araw,
                                                 const short* __restrict__ WTf,
                                                 const float* __restrict__ bias,
                                                 short* __restrict__ C, int M)
{
    constexpr int KS = K / 32;
    constexpr int CT = N / 32;
    constexpr int LK = K + 8;

    __shared__ __align__(16) short As[64][LK];

    const int tid  = threadIdx.x;
    const int wave = tid >> 6;
    const int lane = tid & 63;
    const int l15  = lane & 15;
    const int lk   = (lane >> 4) * 8;
    const int wr   = wave >> 1;
    const int wc   = wave & 1;
    const int r0   = blockIdx.x * 64;

    if (A_F32) {
        const float* Af = (const float*)Araw;
#pragma unroll
        for (int it = 0; it < 64 * (K / 4) / 256; ++it) {
            const int idx = it * 256 + tid;
            const int row = idx / (K / 4);
            const int c4  = idx % (K / 4);
            const int gr  = min(r0 + row, M - 1);
            const float4 v = *reinterpret_cast<const float4*>(&Af[(size_t)gr * K + c4 * 4]);
            short4v s;
            s[0] = f32_to_bf16_bits(v.x); s[1] = f32_to_bf16_bits(v.y);
            s[2] = f32_to_bf16_bits(v.z); s[3] = f32_to_bf16_bits(v.w);
            *reinterpret_cast<short4v*>(&As[row][c4 * 4]) = s;
        }
    } else {
        const short* Ab = (const short*)Araw;
#pragma unroll
        for (int it = 0; it < 64 * (K / 8) / 256; ++it) {
            const int idx = it * 256 + tid;
            const int row = idx / (K / 8);
            const int c8  = idx % (K / 8);
            const int gr  = min(r0 + row, M - 1);
            const short8 v = *reinterpret_cast<const short8*>(&Ab[(size_t)gr * K + c8 * 8]);
            *reinterpret_cast<short8*>(&As[row][c8 * 8]) = v;
        }
    }
    __syncthreads();

    float bv[CT];
#pragma unroll
    for (int t = 0; t < CT; ++t) bv[t] = bias[wc * (N / 2) + t * 16 + l15];

    floatx4 acc[2][CT];
#pragma unroll
    for (int rt = 0; rt < 2; ++rt)
#pragma unroll
        for (int t = 0; t < CT; ++t) acc[rt][t] = (floatx4){0.f, 0.f, 0.f, 0.f};

#pragma unroll
    for (int ks = 0; ks < KS; ++ks) {
        short8 b[CT];
#pragma unroll
        for (int t = 0; t < CT; ++t) {
            const int tg = wc * CT + t;
            b[t] = *reinterpret_cast<const short8*>(&WTf[((size_t)(tg * KS + ks) * 64 + lane) * 8]);
        }
        short8 a[2];
#pragma unroll
        for (int rt = 0; rt < 2; ++rt)
            a[rt] = *reinterpret_cast<const short8*>(&As[wr * 32 + rt * 16 + l15][ks * 32 + lk]);
#pragma unroll
        for (int rt = 0; rt < 2; ++rt)
#pragma unroll
            for (int t = 0; t < CT; ++t)
                acc[rt][t] = __builtin_amdgcn_mfma_f32_16x16x32_bf16(a[rt], b[t], acc[rt][t], 0, 0, 0);
    }

    const int rowg = (lane >> 4) * 4;
#pragma unroll
    for (int rt = 0; rt < 2; ++rt)
#pragma unroll
        for (int t = 0; t < CT; ++t)
#pragma unroll
            for (int j = 0; j < 4; ++j) {
                const int gr = r0 + wr * 32 + rt * 16 + rowg + j;
                if (gr < M)
                    C[(size_t)gr * N + wc * (N / 2) + t * 16 + l15] =
                        f32_to_bf16_bits(acc[rt][t][j] + bv[t]);
            }
}

// ---------------- FUSED: pull (64 nodes, D=128) -> relu -> GEMM ----------------
// Block = 1 bucket = 64 nodes, 8 waves (512 thr). Phase 1: 8 nodes/wave pulled
// into LDS (bf16, relu'd). Phase 2: MFMA 64xK @ KxN from LDS.
template<int K, int N>
__global__ __launch_bounds__(512) void fused_pull_gemm(const unsigned int* __restrict__ h,
                                                       const int* __restrict__ row_ptr,
                                                       const unsigned int* __restrict__ csr_ew,
                                                       const short* __restrict__ WTf,
                                                       const float* __restrict__ bias,
                                                       short* __restrict__ C, int M)
{
    static_assert(K == 128, "pull input dim is 128");
    constexpr int KS   = K / 32;
    constexpr int LK   = K + 8;
    constexpr int COLT = 2;                 // col-tiles per wave
    constexpr int WCG  = N / (COLT * 16);   // 4 (N=128) or 2 (N=64)
    constexpr int WRG  = 8 / WCG;           // 2 or 4
    constexpr int ROWT = 64 / (WRG * 16);   // 2 or 1

    __shared__ __align__(16) short As[64][LK];

    const int tid  = threadIdx.x;
    const int wave = tid >> 6;
    const int lane = tid & 63;
    const int r0   = blockIdx.x * 64;

    // ---- Phase 1: pull 8 nodes per wave ----
    for (int i = 0; i < 8; ++i) {
        const int lrow = wave * 8 + i;
        const int node = r0 + lrow;
        if (node < M) {
            const int beg = row_ptr[node];
            const int end = row_ptr[node + 1];

            float ax[8], ay[8];
#pragma unroll
            for (int u = 0; u < 8; ++u) { ax[u] = 0.f; ay[u] = 0.f; }

            for (int c = beg; c < end; c += 64) {
                const int idx = c + lane;
                const unsigned ew = (idx < end) ? csr_ew[idx] : 0u;
                const int cnt = min(64, end - c);
                for (int j = 0; j < cnt; j += 8) {
                    unsigned e[8];
#pragma unroll
                    for (int u = 0; u < 8; ++u) {
                        const unsigned v = __shfl(ew, j + u);
                        e[u] = (j + u < cnt) ? v : 0u;
                    }
                    unsigned p[8];
#pragma unroll
                    for (int u = 0; u < 8; ++u)
                        p[u] = h[(size_t)(e[u] >> 16) * 64 + lane];
#pragma unroll
                    for (int u = 0; u < 8; ++u) {
                        const float wv = __int_as_float(e[u] << 16);
                        ax[u] = fmaf(__int_as_float(p[u] << 16), wv, ax[u]);
                        ay[u] = fmaf(__int_as_float(p[u] & 0xffff0000u), wv, ay[u]);
                    }
                }
            }
            float axs = ((ax[0] + ax[1]) + (ax[2] + ax[3])) + ((ax[4] + ax[5]) + (ax[6] + ax[7]));
            float ays = ((ay[0] + ay[1]) + (ay[2] + ay[3])) + ((ay[4] + ay[5]) + (ay[6] + ay[7]));
            axs = fmaxf(axs, 0.f); ays = fmaxf(ays, 0.f);      // relu (inputs to next gemm)
            const unsigned lo = (unsigned short)f32_to_bf16_bits(axs);
            const unsigned hi = (unsigned short)f32_to_bf16_bits(ays);
            *reinterpret_cast<unsigned int*>(&As[lrow][2 * lane]) = lo | (hi << 16);
        }
    }
    __syncthreads();

    // ---- Phase 2: GEMM from LDS ----
    const int l15 = lane & 15;
    const int lk  = (lane >> 4) * 8;
    const int wr  = wave / WCG;
    const int wc  = wave % WCG;

    float bv[COLT];
#pragma unroll
    for (int t = 0; t < COLT; ++t) bv[t] = bias[wc * COLT * 16 + t * 16 + l15];

    floatx4 acc[ROWT][COLT];
#pragma unroll
    for (int rt = 0; rt < ROWT; ++rt)
#pragma unroll
        for (int t = 0; t < COLT; ++t) acc[rt][t] = (floatx4){0.f, 0.f, 0.f, 0.f};

#pragma unroll
    for (int ks = 0; ks < KS; ++ks) {
        short8 b[COLT];
#pragma unroll
        for (int t = 0; t < COLT; ++t) {
            const int tg = wc * COLT + t;
            b[t] = *reinterpret_cast<const short8*>(&WTf[((size_t)(tg * KS + ks) * 64 + lane) * 8]);
        }
        short8 a[ROWT];
#pragma unroll
        for (int rt = 0; rt < ROWT; ++rt)
            a[rt] = *reinterpret_cast<const short8*>(&As[wr * (ROWT * 16) + rt * 16 + l15][ks * 32 + lk]);
#pragma unroll
        for (int rt = 0; rt < ROWT; ++rt)
#pragma unroll
            for (int t = 0; t < COLT; ++t)
                acc[rt][t] = __builtin_amdgcn_mfma_f32_16x16x32_bf16(a[rt], b[t], acc[rt][t], 0, 0, 0);
    }

    const int rowg = (lane >> 4) * 4;
#pragma unroll
    for (int rt = 0; rt < ROWT; ++rt)
#pragma unroll
        for (int t = 0; t < COLT; ++t)
#pragma unroll
            for (int j = 0; j < 4; ++j) {
                const int gr = r0 + wr * (ROWT * 16) + rt * 16 + rowg + j;
                if (gr < M)
                    C[(size_t)gr * N + wc * COLT * 16 + t * 16 + l15] =
                        f32_to_bf16_bits(acc[rt][t][j] + bv[t]);
            }
}

// ---------------- W -> fragment-ordered bf16 WTf ----------------
__device__ inline void wt_frag(const float* __restrict__ W, short* __restrict__ out,
                               int K, int N, int u)
{
    const int lane = u & 63;
    const int rest = u >> 6;
    const int KS   = K >> 5;
    const int ks   = rest % KS;
    const int tg   = rest / KS;
    const int n    = tg * 16 + (lane & 15);
    const int kb   = ks * 32 + (lane >> 4) * 8;
    short8 s;
#pragma unroll
    for (int e = 0; e < 8; ++e) s[e] = f32_to_bf16_bits(W[(size_t)(kb + e) * N + n]);
    *reinterpret_cast<short8*>(&out[(size_t)u * 8]) = s;
}

// ================= prep: bin_hist (blocks 0..255) + wt transposes (blocks 256..283) ===========
__global__ __launch_bounds__(256) void prep_kernel(const int* __restrict__ dst,
                                                   int* __restrict__ hist_g, int E,
                                                   const float* __restrict__ W1, short* __restrict__ WT1,
                                                   const float* __restrict__ W2, short* __restrict__ WT2,
                                                   const float* __restrict__ W3, short* __restrict__ WT3)
{
    if (blockIdx.x < BIN_BLOCKS) {
        __shared__ int hist[NBUCK];
        for (int t = threadIdx.x; t < NBUCK; t += 256) hist[t] = 0;
        __syncthreads();
        const int chunk = (E + BIN_BLOCKS - 1) / BIN_BLOCKS;
        const int beg = blockIdx.x * chunk;
        const int end = min(beg + chunk, E);
        for (int i = beg + threadIdx.x; i < end; i += 256)
            atomicAdd(&hist[dst[i] >> BSHIFT], 1);
        __syncthreads();
        for (int t = threadIdx.x; t < NBUCK; t += 256)
            hist_g[blockIdx.x * NBUCK + t] = hist[t];
    } else {
        const int u = (blockIdx.x - BIN_BLOCKS) * 256 + threadIdx.x;
        if (u < 4096)             wt_frag(W1, WT1, 256, 128, u);
        else if (u < 4096 + 2048) wt_frag(W2, WT2, 128, 128, u - 4096);
        else if (u < 7168)        wt_frag(W3, WT3, 128, 64,  u - 6144);
    }
}

__global__ __launch_bounds__(256) void bin_scan_blocks(const int* __restrict__ hist_g,
                                                       int* __restrict__ blockbase,
                                                       int* __restrict__ tot)
{
    __shared__ int s[BIN_BLOCKS];
    const int b = blockIdx.x;
    const int t = threadIdx.x;
    const int v = hist_g[t * NBUCK + b];
    s[t] = v;
    __syncthreads();
#pragma unroll
    for (int off = 1; off < BIN_BLOCKS; off <<= 1) {
        const int tmp = (t >= off) ? s[t - off] : 0;
        __syncthreads();
        s[t] += tmp;
        __syncthreads();
    }
    blockbase[t * NBUCK + b] = s[t] - v;
    if (t == BIN_BLOCKS - 1) tot[b] = s[t];
}

__global__ __launch_bounds__(256) void bin_scan_tot(const int* __restrict__ tot,
                                                    int* __restrict__ bucket_base)
{
    __shared__ int psum[256];
    const int t = threadIdx.x;
    int vals[4];
    int s = 0;
#pragma unroll
    for (int j = 0; j < 4; ++j) {
        const int idx = t * 4 + j;
        vals[j] = (idx < NBUCK) ? tot[idx] : 0;
        s += vals[j];
    }
    psum[t] = s;
    __syncthreads();
#pragma unroll
    for (int off = 1; off < 256; off <<= 1) {
        const int tmp = (t >= off) ? psum[t - off] : 0;
        __syncthreads();
        psum[t] += tmp;
        __syncthreads();
    }
    int run = psum[t] - s;
#pragma unroll
    for (int j = 0; j < 4; ++j) {
        const int idx = t * 4 + j;
        if (idx < NBUCK) bucket_base[idx] = run;
        run += vals[j];
    }
    if (t == 255) bucket_base[NBUCK] = run;
}

__global__ __launch_bounds__(256) void bin_write(const int* __restrict__ src,
                                                 const int* __restrict__ dst,
                                                 const float* __restrict__ w,
                                                 const int* __restrict__ blockbase,
                                                 const int* __restrict__ bucket_base,
                                                 int2* __restrict__ tmp, int E)
{
    __shared__ int cur[NBUCK];
    for (int t = threadIdx.x; t < NBUCK; t += 256)
        cur[t] = bucket_base[t] + blockbase[blockIdx.x * NBUCK + t];
    __syncthreads();
    const int chunk = (E + BIN_BLOCKS - 1) / BIN_BLOCKS;
    const int beg = blockIdx.x * chunk;
    const int end = min(beg + chunk, E);
    for (int i = beg + threadIdx.x; i < end; i += 256) {
        const int d = dst[i];
        const int pos = atomicAdd(&cur[d >> BSHIFT], 1);
        tmp[pos] = make_int2((src[i] << BSHIFT) | (d & (BSIZE - 1)), __float_as_int(w[i]));
    }
}

// Pass D: one block per bucket. row_ptr + node-sorted packed 4B csr: (src<<16)|bf16(w)
__global__ __launch_bounds__(256) void fine_fill2(const int2* __restrict__ tmp,
                                                  const int* __restrict__ bucket_base,
                                                  unsigned int* __restrict__ csr_ew,
                                                  int* __restrict__ row_ptr)
{
    __shared__ int hist[BSIZE];
    __shared__ int basel[BSIZE];
    const int b    = blockIdx.x;
    const int t    = threadIdx.x;
    const int rbeg = bucket_base[b];
    const int rend = bucket_base[b + 1];

    if (t < BSIZE) hist[t] = 0;
    __syncthreads();
    for (int i = rbeg + t; i < rend; i += 256)
        atomicAdd(&hist[((unsigned)tmp[i].x) & (BSIZE - 1)], 1);
    __syncthreads();

    if (t < BSIZE) {
        const int v = hist[t];
        int inc = v;
#pragma unroll
        for (int off = 1; off < BSIZE; off <<= 1) {
            const int u = __shfl_up(inc, off, 64);
            if (t >= off) inc += u;
        }
        const int excl = rbeg + inc - v;
        basel[t] = excl;
        const int node = (b << BSHIFT) + t;
        if (node < N_NODES) row_ptr[node] = excl;
        if (b == NBUCK - 1 && t == 0) row_ptr[N_NODES] = bucket_base[NBUCK];
    }
    __syncthreads();

    for (int i = rbeg + t; i < rend; i += 256) {
        const int2 e = tmp[i];
        const unsigned ex = (unsigned)e.x;
        const int pos = atomicAdd(&basel[ex & (BSIZE - 1)], 1);
        const unsigned wb = (unsigned short)f32_to_bf16_bits(__int_as_float(e.y));
        csr_ew[pos] = ((ex >> BSHIFT) << 16) | wb;
    }
}

// ---------------- pull (bf16 h, D=64): two nodes per wave, f32 out (final layer) ----------------
__global__ __launch_bounds__(256) void pull64_bf(const unsigned int* __restrict__ h,
                                                 const int* __restrict__ row_ptr,
                                                 const unsigned int* __restrict__ csr_ew,
                                                 float2* __restrict__ out, int n_nodes)
{
    const int wave = threadIdx.x >> 6;
    const int lane = threadIdx.x & 63;
    const int half = lane >> 5;
    const int l32  = lane & 31;
    const int node = blockIdx.x * 8 + wave * 2 + half;
    if (node >= n_nodes) return;

    const int beg = row_ptr[node];
    const int end = row_ptr[node + 1];

    float ax[8], ay[8];
#pragma unroll
    for (int u = 0; u < 8; ++u) { ax[u] = 0.f; ay[u] = 0.f; }

    for (int c = beg; c < end; c += 32) {
        const int idx = c + l32;
        const unsigned ew = (idx < end) ? csr_ew[idx] : 0u;
        const int cnt = min(32, end - c);
        for (int j = 0; j < cnt; j += 8) {
            unsigned e[8];
#pragma unroll
            for (int u = 0; u < 8; ++u) {
                const unsigned v = __shfl(ew, j + u, 32);
                e[u] = (j + u < cnt) ? v : 0u;
            }
            unsigned p[8];
#pragma unroll
            for (int u = 0; u < 8; ++u)
                p[u] = h[(size_t)(e[u] >> 16) * 32 + l32];
#pragma unroll
            for (int u = 0; u < 8; ++u) {
                const float wv = __int_as_float(e[u] << 16);
                ax[u] = fmaf(__int_as_float(p[u] << 16), wv, ax[u]);
                ay[u] = fmaf(__int_as_float(p[u] & 0xffff0000u), wv, ay[u]);
            }
        }
    }

    const float axs = ((ax[0] + ax[1]) + (ax[2] + ax[3])) + ((ax[4] + ax[5]) + (ax[6] + ax[7]));
    const float ays = ((ay[0] + ay[1]) + (ay[2] + ay[3])) + ((ay[4] + ay[5]) + (ay[6] + ay[7]));
    out[(size_t)node * 32 + l32] = make_float2(axs, ays);
}

extern "C" void kernel_launch(void* const* d_in, const int* in_sizes, int n_in,
                              void* d_out, int out_size, void* d_ws, size_t ws_size,
                              hipStream_t stream)
{
    const float* x   = (const float*)d_in[0];
    const int*   src = (const int*)  d_in[1];
    const int*   dst = (const int*)  d_in[2];
    const float* w   = (const float*)d_in[3];
    const float* W1  = (const float*)d_in[4];
    const float* b1  = (const float*)d_in[5];
    const float* W2  = (const float*)d_in[6];
    const float* b2  = (const float*)d_in[7];
    const float* W3  = (const float*)d_in[8];
    const float* b3  = (const float*)d_in[9];

    const int E = in_sizes[1];
    const int M = N_NODES;

    // workspace layout
    short* hA  = (short*)d_ws;                        // M*128 bf16 (h1 / h3)
    short* hB  = hA + (size_t)M * 128;                // M*128 bf16 (h2)
    short* WT1 = hB + (size_t)M * 128;                // frag-ordered
    short* WT2 = WT1 + 128 * 256;
    short* WT3 = WT2 + 128 * 128;
    unsigned int* csr_ew = (unsigned int*)(WT3 + 64 * 128);  // E u32
    int2*  tmp_ew      = (int2*)(csr_ew + ((E + 1) & ~1));   // E pairs
    int*   row_ptr     = (int*)(tmp_ew + E);          // 50048
    int*   hist_g      = row_ptr + 50048;             // 256*782 -> pad 200704
    int*   blockbase   = hist_g + 200704;             // 256*782 -> pad 200704
    int*   bucket_base = blockbase + 200704;          // 783 -> pad 1024
    int*   tot         = bucket_base + 1024;          // 782 -> pad 1024

    // ---- build (weights + CSR), no global atomics ----
    prep_kernel<<<BIN_BLOCKS + 28, 256, 0, stream>>>(dst, hist_g, E, W1, WT1, W2, WT2, W3, WT3);
    bin_scan_blocks<<<NBUCK, BIN_BLOCKS, 0, stream>>>(hist_g, blockbase, tot);
    bin_scan_tot<<<1, 256, 0, stream>>>(tot, bucket_base);
    bin_write<<<BIN_BLOCKS, 256, 0, stream>>>(src, dst, w, blockbase, bucket_base, tmp_ew, E);
    fine_fill2<<<NBUCK, 256, 0, stream>>>(tmp_ew, bucket_base, csr_ew, row_ptr);

    // ---- Layer 1 GEMM: x @ W1 -> h1 (hA) ----
    mfma_gemm<256, 128, true><<<NBUCK, 256, 0, stream>>>(x, WT1, b1, hA, M);

    // ---- Fused: pull(h1) -> relu -> @W2 -> h2 (hB) ----
    fused_pull_gemm<128, 128><<<NBUCK, 512, 0, stream>>>((const unsigned int*)hA, row_ptr, csr_ew,
                                                         WT2, b2, hB, M);
    // ---- Fused: pull(h2) -> relu -> @W3 -> h3 (hA) ----
    fused_pull_gemm<128, 64><<<NBUCK, 512, 0, stream>>>((const unsigned int*)hB, row_ptr, csr_ew,
                                                        WT3, b3, hA, M);
    // ---- Final pull: out = segsum(h3) ----
    pull64_bf<<<(M + 7) / 8, 256, 0, stream>>>((const unsigned int*)hA, row_ptr, csr_ew,
                                               (float2*)d_out, M);
}

// Round 13
// 145.401 us; speedup vs baseline: 2.7664x; 1.0149x over previous
//
#include <hip/hip_runtime.h>
#include <hip/hip_bf16.h>

#define N_NODES 50000
#define BSHIFT  6
#define BSIZE   64
#define NBUCK   ((N_NODES + BSIZE - 1) / BSIZE)   // 782
#define BIN_BLOCKS 256

using short8  = __attribute__((ext_vector_type(8))) short;
using short4v = __attribute__((ext_vector_type(4))) short;
using floatx4 = __attribute__((ext_vector_type(4))) float;

__device__ inline short f32_to_bf16_bits(float f) {
    __hip_bfloat16 h = __float2bfloat16(f);
    return *reinterpret_cast<short*>(&h);
}

// ---------------- MFMA GEMM (layer 1 only): coalesced loads ----------------
template<int K, int N, bool A_F32>
__global__ __launch_bounds__(256) void mfma_gemm(const void* __restrict__ Araw,
                                                 const short* __restrict__ WTf,
                                                 const float* __restrict__ bias,
                                                 short* __restrict__ C, int M)
{
    constexpr int KS = K / 32;
    constexpr int CT = N / 32;
    constexpr int LK = K + 8;

    __shared__ __align__(16) short As[64][LK];

    const int tid  = threadIdx.x;
    const int wave = tid >> 6;
    const int lane = tid & 63;
    const int l15  = lane & 15;
    const int lk   = (lane >> 4) * 8;
    const int wr   = wave >> 1;
    const int wc   = wave & 1;
    const int r0   = blockIdx.x * 64;

    if (A_F32) {
        const float* Af = (const float*)Araw;
#pragma unroll
        for (int it = 0; it < 64 * (K / 4) / 256; ++it) {
            const int idx = it * 256 + tid;
            const int row = idx / (K / 4);
            const int c4  = idx % (K / 4);
            const int gr  = min(r0 + row, M - 1);
            const float4 v = *reinterpret_cast<const float4*>(&Af[(size_t)gr * K + c4 * 4]);
            short4v s;
            s[0] = f32_to_bf16_bits(v.x); s[1] = f32_to_bf16_bits(v.y);
            s[2] = f32_to_bf16_bits(v.z); s[3] = f32_to_bf16_bits(v.w);
            *reinterpret_cast<short4v*>(&As[row][c4 * 4]) = s;
        }
    } else {
        const short* Ab = (const short*)Araw;
#pragma unroll
        for (int it = 0; it < 64 * (K / 8) / 256; ++it) {
            const int idx = it * 256 + tid;
            const int row = idx / (K / 8);
            const int c8  = idx % (K / 8);
            const int gr  = min(r0 + row, M - 1);
            const short8 v = *reinterpret_cast<const short8*>(&Ab[(size_t)gr * K + c8 * 8]);
            *reinterpret_cast<short8*>(&As[row][c8 * 8]) = v;
        }
    }
    __syncthreads();

    float bv[CT];
#pragma unroll
    for (int t = 0; t < CT; ++t) bv[t] = bias[wc * (N / 2) + t * 16 + l15];

    floatx4 acc[2][CT];
#pragma unroll
    for (int rt = 0; rt < 2; ++rt)
#pragma unroll
        for (int t = 0; t < CT; ++t) acc[rt][t] = (floatx4){0.f, 0.f, 0.f, 0.f};

#pragma unroll
    for (int ks = 0; ks < KS; ++ks) {
        short8 b[CT];
#pragma unroll
        for (int t = 0; t < CT; ++t) {
            const int tg = wc * CT + t;
            b[t] = *reinterpret_cast<const short8*>(&WTf[((size_t)(tg * KS + ks) * 64 + lane) * 8]);
        }
        short8 a[2];
#pragma unroll
        for (int rt = 0; rt < 2; ++rt)
            a[rt] = *reinterpret_cast<const short8*>(&As[wr * 32 + rt * 16 + l15][ks * 32 + lk]);
#pragma unroll
        for (int rt = 0; rt < 2; ++rt)
#pragma unroll
            for (int t = 0; t < CT; ++t)
                acc[rt][t] = __builtin_amdgcn_mfma_f32_16x16x32_bf16(a[rt], b[t], acc[rt][t], 0, 0, 0);
    }

    const int rowg = (lane >> 4) * 4;
#pragma unroll
    for (int rt = 0; rt < 2; ++rt)
#pragma unroll
        for (int t = 0; t < CT; ++t)
#pragma unroll
            for (int j = 0; j < 4; ++j) {
                const int gr = r0 + wr * 32 + rt * 16 + rowg + j;
                if (gr < M)
                    C[(size_t)gr * N + wc * (N / 2) + t * 16 + l15] =
                        f32_to_bf16_bits(acc[rt][t][j] + bv[t]);
            }
}

// ---------------- FUSED: pull (64 nodes, D=128) -> relu -> GEMM ----------------
// Block = 1 bucket = 64 nodes, 16 waves (1024 thr). Phase 1: 4 nodes/wave.
// Phase 2: MFMA 64xK @ KxN from LDS, wave = 1 col-tile x ROWT row-tiles.
template<int K, int N>
__global__ __launch_bounds__(1024) void fused_pull_gemm(const unsigned int* __restrict__ h,
                                                        const int* __restrict__ row_ptr,
                                                        const unsigned int* __restrict__ csr_ew,
                                                        const short* __restrict__ WTf,
                                                        const float* __restrict__ bias,
                                                        short* __restrict__ C, int M)
{
    static_assert(K == 128, "pull input dim is 128");
    constexpr int KS   = K / 32;
    constexpr int LK   = K + 8;
    constexpr int WCG  = N / 16;            // col groups (8 for N=128, 4 for N=64)
    constexpr int WRG  = 16 / WCG;          // row groups (2 or 4)
    constexpr int ROWT = 64 / (WRG * 16);   // row tiles per wave (2 or 1)

    __shared__ __align__(16) short As[64][LK];

    const int tid  = threadIdx.x;
    const int wave = tid >> 6;
    const int lane = tid & 63;
    const int r0   = blockIdx.x * 64;

    // ---- Phase 1: pull 4 nodes per wave ----
    for (int i = 0; i < 4; ++i) {
        const int lrow = wave * 4 + i;
        const int node = r0 + lrow;
        if (node < M) {
            const int beg = row_ptr[node];
            const int end = row_ptr[node + 1];

            float ax[8], ay[8];
#pragma unroll
            for (int u = 0; u < 8; ++u) { ax[u] = 0.f; ay[u] = 0.f; }

            for (int c = beg; c < end; c += 64) {
                const int idx = c + lane;
                const unsigned ew = (idx < end) ? csr_ew[idx] : 0u;
                const int cnt = min(64, end - c);
                for (int j = 0; j < cnt; j += 8) {
                    unsigned e[8];
#pragma unroll
                    for (int u = 0; u < 8; ++u) {
                        const unsigned v = __shfl(ew, j + u);
                        e[u] = (j + u < cnt) ? v : 0u;
                    }
                    unsigned p[8];
#pragma unroll
                    for (int u = 0; u < 8; ++u)
                        p[u] = h[(size_t)(e[u] >> 16) * 64 + lane];
#pragma unroll
                    for (int u = 0; u < 8; ++u) {
                        const float wv = __int_as_float(e[u] << 16);
                        ax[u] = fmaf(__int_as_float(p[u] << 16), wv, ax[u]);
                        ay[u] = fmaf(__int_as_float(p[u] & 0xffff0000u), wv, ay[u]);
                    }
                }
            }
            float axs = ((ax[0] + ax[1]) + (ax[2] + ax[3])) + ((ax[4] + ax[5]) + (ax[6] + ax[7]));
            float ays = ((ay[0] + ay[1]) + (ay[2] + ay[3])) + ((ay[4] + ay[5]) + (ay[6] + ay[7]));
            axs = fmaxf(axs, 0.f); ays = fmaxf(ays, 0.f);      // relu
            const unsigned lo = (unsigned short)f32_to_bf16_bits(axs);
            const unsigned hi = (unsigned short)f32_to_bf16_bits(ays);
            *reinterpret_cast<unsigned int*>(&As[lrow][2 * lane]) = lo | (hi << 16);
        }
    }
    __syncthreads();

    // ---- Phase 2: GEMM from LDS ----
    const int l15 = lane & 15;
    const int lk  = (lane >> 4) * 8;
    const int wr  = wave / WCG;
    const int wc  = wave % WCG;

    const float bv = bias[wc * 16 + l15];

    floatx4 acc[ROWT];
#pragma unroll
    for (int rt = 0; rt < ROWT; ++rt) acc[rt] = (floatx4){0.f, 0.f, 0.f, 0.f};

#pragma unroll
    for (int ks = 0; ks < KS; ++ks) {
        const short8 b = *reinterpret_cast<const short8*>(
            &WTf[((size_t)(wc * KS + ks) * 64 + lane) * 8]);
        short8 a[ROWT];
#pragma unroll
        for (int rt = 0; rt < ROWT; ++rt)
            a[rt] = *reinterpret_cast<const short8*>(
                &As[wr * (ROWT * 16) + rt * 16 + l15][ks * 32 + lk]);
#pragma unroll
        for (int rt = 0; rt < ROWT; ++rt)
            acc[rt] = __builtin_amdgcn_mfma_f32_16x16x32_bf16(a[rt], b, acc[rt], 0, 0, 0);
    }

    const int rowg = (lane >> 4) * 4;
#pragma unroll
    for (int rt = 0; rt < ROWT; ++rt)
#pragma unroll
        for (int j = 0; j < 4; ++j) {
            const int gr = r0 + wr * (ROWT * 16) + rt * 16 + rowg + j;
            if (gr < M)
                C[(size_t)gr * N + wc * 16 + l15] = f32_to_bf16_bits(acc[rt][j] + bv);
        }
}

// ---------------- W -> fragment-ordered bf16 WTf ----------------
__device__ inline void wt_frag(const float* __restrict__ W, short* __restrict__ out,
                               int K, int N, int u)
{
    const int lane = u & 63;
    const int rest = u >> 6;
    const int KS   = K >> 5;
    const int ks   = rest % KS;
    const int tg   = rest / KS;
    const int n    = tg * 16 + (lane & 15);
    const int kb   = ks * 32 + (lane >> 4) * 8;
    short8 s;
#pragma unroll
    for (int e = 0; e < 8; ++e) s[e] = f32_to_bf16_bits(W[(size_t)(kb + e) * N + n]);
    *reinterpret_cast<short8*>(&out[(size_t)u * 8]) = s;
}

// ================= prep: bin_hist (blocks 0..255) + wt transposes =================
__global__ __launch_bounds__(256) void prep_kernel(const int* __restrict__ dst,
                                                   int* __restrict__ hist_g, int E,
                                                   const float* __restrict__ W1, short* __restrict__ WT1,
                                                   const float* __restrict__ W2, short* __restrict__ WT2,
                                                   const float* __restrict__ W3, short* __restrict__ WT3)
{
    if (blockIdx.x < BIN_BLOCKS) {
        __shared__ int hist[NBUCK];
        for (int t = threadIdx.x; t < NBUCK; t += 256) hist[t] = 0;
        __syncthreads();
        const int chunk = (E + BIN_BLOCKS - 1) / BIN_BLOCKS;
        const int beg = blockIdx.x * chunk;
        const int end = min(beg + chunk, E);
        for (int i = beg + threadIdx.x; i < end; i += 256)
            atomicAdd(&hist[dst[i] >> BSHIFT], 1);
        __syncthreads();
        for (int t = threadIdx.x; t < NBUCK; t += 256)
            hist_g[blockIdx.x * NBUCK + t] = hist[t];
    } else {
        const int u = (blockIdx.x - BIN_BLOCKS) * 256 + threadIdx.x;
        if (u < 4096)             wt_frag(W1, WT1, 256, 128, u);
        else if (u < 4096 + 2048) wt_frag(W2, WT2, 128, 128, u - 4096);
        else if (u < 7168)        wt_frag(W3, WT3, 128, 64,  u - 6144);
    }
}

__global__ __launch_bounds__(256) void bin_scan_blocks(const int* __restrict__ hist_g,
                                                       int* __restrict__ blockbase,
                                                       int* __restrict__ tot)
{
    __shared__ int s[BIN_BLOCKS];
    const int b = blockIdx.x;
    const int t = threadIdx.x;
    const int v = hist_g[t * NBUCK + b];
    s[t] = v;
    __syncthreads();
#pragma unroll
    for (int off = 1; off < BIN_BLOCKS; off <<= 1) {
        const int tmp = (t >= off) ? s[t - off] : 0;
        __syncthreads();
        s[t] += tmp;
        __syncthreads();
    }
    blockbase[t * NBUCK + b] = s[t] - v;
    if (t == BIN_BLOCKS - 1) tot[b] = s[t];
}

__global__ __launch_bounds__(256) void bin_scan_tot(const int* __restrict__ tot,
                                                    int* __restrict__ bucket_base)
{
    __shared__ int psum[256];
    const int t = threadIdx.x;
    int vals[4];
    int s = 0;
#pragma unroll
    for (int j = 0; j < 4; ++j) {
        const int idx = t * 4 + j;
        vals[j] = (idx < NBUCK) ? tot[idx] : 0;
        s += vals[j];
    }
    psum[t] = s;
    __syncthreads();
#pragma unroll
    for (int off = 1; off < 256; off <<= 1) {
        const int tmp = (t >= off) ? psum[t - off] : 0;
        __syncthreads();
        psum[t] += tmp;
        __syncthreads();
    }
    int run = psum[t] - s;
#pragma unroll
    for (int j = 0; j < 4; ++j) {
        const int idx = t * 4 + j;
        if (idx < NBUCK) bucket_base[idx] = run;
        run += vals[j];
    }
    if (t == 255) bucket_base[NBUCK] = run;
}

__global__ __launch_bounds__(256) void bin_write(const int* __restrict__ src,
                                                 const int* __restrict__ dst,
                                                 const float* __restrict__ w,
                                                 const int* __restrict__ blockbase,
                                                 const int* __restrict__ bucket_base,
                                                 int2* __restrict__ tmp, int E)
{
    __shared__ int cur[NBUCK];
    for (int t = threadIdx.x; t < NBUCK; t += 256)
        cur[t] = bucket_base[t] + blockbase[blockIdx.x * NBUCK + t];
    __syncthreads();
    const int chunk = (E + BIN_BLOCKS - 1) / BIN_BLOCKS;
    const int beg = blockIdx.x * chunk;
    const int end = min(beg + chunk, E);
    for (int i = beg + threadIdx.x; i < end; i += 256) {
        const int d = dst[i];
        const int pos = atomicAdd(&cur[d >> BSHIFT], 1);
        tmp[pos] = make_int2((src[i] << BSHIFT) | (d & (BSIZE - 1)), __float_as_int(w[i]));
    }
}

// Pass D: one block per bucket. row_ptr + node-sorted packed 4B csr: (src<<16)|bf16(w)
__global__ __launch_bounds__(256) void fine_fill2(const int2* __restrict__ tmp,
                                                  const int* __restrict__ bucket_base,
                                                  unsigned int* __restrict__ csr_ew,
                                                  int* __restrict__ row_ptr)
{
    __shared__ int hist[BSIZE];
    __shared__ int basel[BSIZE];
    const int b    = blockIdx.x;
    const int t    = threadIdx.x;
    const int rbeg = bucket_base[b];
    const int rend = bucket_base[b + 1];

    if (t < BSIZE) hist[t] = 0;
    __syncthreads();
    for (int i = rbeg + t; i < rend; i += 256)
        atomicAdd(&hist[((unsigned)tmp[i].x) & (BSIZE - 1)], 1);
    __syncthreads();

    if (t < BSIZE) {
        const int v = hist[t];
        int inc = v;
#pragma unroll
        for (int off = 1; off < BSIZE; off <<= 1) {
            const int u = __shfl_up(inc, off, 64);
            if (t >= off) inc += u;
        }
        const int excl = rbeg + inc - v;
        basel[t] = excl;
        const int node = (b << BSHIFT) + t;
        if (node < N_NODES) row_ptr[node] = excl;
        if (b == NBUCK - 1 && t == 0) row_ptr[N_NODES] = bucket_base[NBUCK];
    }
    __syncthreads();

    for (int i = rbeg + t; i < rend; i += 256) {
        const int2 e = tmp[i];
        const unsigned ex = (unsigned)e.x;
        const int pos = atomicAdd(&basel[ex & (BSIZE - 1)], 1);
        const unsigned wb = (unsigned short)f32_to_bf16_bits(__int_as_float(e.y));
        csr_ew[pos] = ((ex >> BSHIFT) << 16) | wb;
    }
}

// ---------------- pull (bf16 h, D=64): two nodes per wave, f32 out (final layer) ----------------
__global__ __launch_bounds__(256) void pull64_bf(const unsigned int* __restrict__ h,
                                                 const int* __restrict__ row_ptr,
                                                 const unsigned int* __restrict__ csr_ew,
                                                 float2* __restrict__ out, int n_nodes)
{
    const int wave = threadIdx.x >> 6;
    const int lane = threadIdx.x & 63;
    const int half = lane >> 5;
    const int l32  = lane & 31;
    const int node = blockIdx.x * 8 + wave * 2 + half;
    if (node >= n_nodes) return;

    const int beg = row_ptr[node];
    const int end = row_ptr[node + 1];

    float ax[8], ay[8];
#pragma unroll
    for (int u = 0; u < 8; ++u) { ax[u] = 0.f; ay[u] = 0.f; }

    for (int c = beg; c < end; c += 32) {
        const int idx = c + l32;
        const unsigned ew = (idx < end) ? csr_ew[idx] : 0u;
        const int cnt = min(32, end - c);
        for (int j = 0; j < cnt; j += 8) {
            unsigned e[8];
#pragma unroll
            for (int u = 0; u < 8; ++u) {
                const unsigned v = __shfl(ew, j + u, 32);
                e[u] = (j + u < cnt) ? v : 0u;
            }
            unsigned p[8];
#pragma unroll
            for (int u = 0; u < 8; ++u)
                p[u] = h[(size_t)(e[u] >> 16) * 32 + l32];
#pragma unroll
            for (int u = 0; u < 8; ++u) {
                const float wv = __int_as_float(e[u] << 16);
                ax[u] = fmaf(__int_as_float(p[u] << 16), wv, ax[u]);
                ay[u] = fmaf(__int_as_float(p[u] & 0xffff0000u), wv, ay[u]);
            }
        }
    }

    const float axs = ((ax[0] + ax[1]) + (ax[2] + ax[3])) + ((ax[4] + ax[5]) + (ax[6] + ax[7]));
    const float ays = ((ay[0] + ay[1]) + (ay[2] + ay[3])) + ((ay[4] + ay[5]) + (ay[6] + ay[7]));
    out[(size_t)node * 32 + l32] = make_float2(axs, ays);
}

extern "C" void kernel_launch(void* const* d_in, const int* in_sizes, int n_in,
                              void* d_out, int out_size, void* d_ws, size_t ws_size,
                              hipStream_t stream)
{
    const float* x   = (const float*)d_in[0];
    const int*   src = (const int*)  d_in[1];
    const int*   dst = (const int*)  d_in[2];
    const float* w   = (const float*)d_in[3];
    const float* W1  = (const float*)d_in[4];
    const float* b1  = (const float*)d_in[5];
    const float* W2  = (const float*)d_in[6];
    const float* b2  = (const float*)d_in[7];
    const float* W3  = (const float*)d_in[8];
    const float* b3  = (const float*)d_in[9];

    const int E = in_sizes[1];
    const int M = N_NODES;

    // workspace layout
    short* hA  = (short*)d_ws;                        // M*128 bf16 (h1 / h3)
    short* hB  = hA + (size_t)M * 128;                // M*128 bf16 (h2)
    short* WT1 = hB + (size_t)M * 128;                // frag-ordered
    short* WT2 = WT1 + 128 * 256;
    short* WT3 = WT2 + 128 * 128;
    unsigned int* csr_ew = (unsigned int*)(WT3 + 64 * 128);  // E u32
    int2*  tmp_ew      = (int2*)(csr_ew + ((E + 1) & ~1));   // E pairs
    int*   row_ptr     = (int*)(tmp_ew + E);          // 50048
    int*   hist_g      = row_ptr + 50048;             // 256*782 -> pad 200704
    int*   blockbase   = hist_g + 200704;             // 256*782 -> pad 200704
    int*   bucket_base = blockbase + 200704;          // 783 -> pad 1024
    int*   tot         = bucket_base + 1024;          // 782 -> pad 1024

    // ---- build (weights + CSR), no global atomics ----
    prep_kernel<<<BIN_BLOCKS + 28, 256, 0, stream>>>(dst, hist_g, E, W1, WT1, W2, WT2, W3, WT3);
    bin_scan_blocks<<<NBUCK, BIN_BLOCKS, 0, stream>>>(hist_g, blockbase, tot);
    bin_scan_tot<<<1, 256, 0, stream>>>(tot, bucket_base);
    bin_write<<<BIN_BLOCKS, 256, 0, stream>>>(src, dst, w, blockbase, bucket_base, tmp_ew, E);
    fine_fill2<<<NBUCK, 256, 0, stream>>>(tmp_ew, bucket_base, csr_ew, row_ptr);

    // ---- Layer 1 GEMM: x @ W1 -> h1 (hA) ----
    mfma_gemm<256, 128, true><<<NBUCK, 256, 0, stream>>>(x, WT1, b1, hA, M);

    // ---- Fused: pull(h1) -> relu -> @W2 -> h2 (hB) ----
    fused_pull_gemm<128, 128><<<NBUCK, 1024, 0, stream>>>((const unsigned int*)hA, row_ptr, csr_ew,
                                                          WT2, b2, hB, M);
    // ---- Fused: pull(h2) -> relu -> @W3 -> h3 (hA) ----
    fused_pull_gemm<128, 64><<<NBUCK, 1024, 0, stream>>>((const unsigned int*)hB, row_ptr, csr_ew,
                                                         WT3, b3, hA, M);
    // ---- Final pull: out = segsum(h3) ----
    pull64_bf<<<(M + 7) / 8, 256, 0, stream>>>((const unsigned int*)hA, row_ptr, csr_ew,
                                               (float2*)d_out, M);
}

// Round 14
// 141.898 us; speedup vs baseline: 2.8347x; 1.0247x over previous
//
#include <hip/hip_runtime.h>
#include <hip/hip_bf16.h>

#define N_NODES 50000
#define BSHIFT  6
#define BSIZE   64
#define NBUCK   ((N_NODES + BSIZE - 1) / BSIZE)   // 782
#define BIN_BLOCKS 256

using short8  = __attribute__((ext_vector_type(8))) short;
using short4v = __attribute__((ext_vector_type(4))) short;
using floatx4 = __attribute__((ext_vector_type(4))) float;

__device__ inline short f32_to_bf16_bits(float f) {
    __hip_bfloat16 h = __float2bfloat16(f);
    return *reinterpret_cast<short*>(&h);
}

// ---------------- MFMA GEMM (layer 1 only): coalesced loads ----------------
template<int K, int N, bool A_F32>
__global__ __launch_bounds__(256) void mfma_gemm(const void* __restrict__ Araw,
                                                 const short* __restrict__ WTf,
                                                 const float* __restrict__ bias,
                                                 short* __restrict__ C, int M)
{
    constexpr int KS = K / 32;
    constexpr int CT = N / 32;
    constexpr int LK = K + 8;

    __shared__ __align__(16) short As[64][LK];

    const int tid  = threadIdx.x;
    const int wave = tid >> 6;
    const int lane = tid & 63;
    const int l15  = lane & 15;
    const int lk   = (lane >> 4) * 8;
    const int wr   = wave >> 1;
    const int wc   = wave & 1;
    const int r0   = blockIdx.x * 64;

    if (A_F32) {
        const float* Af = (const float*)Araw;
#pragma unroll
        for (int it = 0; it < 64 * (K / 4) / 256; ++it) {
            const int idx = it * 256 + tid;
            const int row = idx / (K / 4);
            const int c4  = idx % (K / 4);
            const int gr  = min(r0 + row, M - 1);
            const float4 v = *reinterpret_cast<const float4*>(&Af[(size_t)gr * K + c4 * 4]);
            short4v s;
            s[0] = f32_to_bf16_bits(v.x); s[1] = f32_to_bf16_bits(v.y);
            s[2] = f32_to_bf16_bits(v.z); s[3] = f32_to_bf16_bits(v.w);
            *reinterpret_cast<short4v*>(&As[row][c4 * 4]) = s;
        }
    } else {
        const short* Ab = (const short*)Araw;
#pragma unroll
        for (int it = 0; it < 64 * (K / 8) / 256; ++it) {
            const int idx = it * 256 + tid;
            const int row = idx / (K / 8);
            const int c8  = idx % (K / 8);
            const int gr  = min(r0 + row, M - 1);
            const short8 v = *reinterpret_cast<const short8*>(&Ab[(size_t)gr * K + c8 * 8]);
            *reinterpret_cast<short8*>(&As[row][c8 * 8]) = v;
        }
    }
    __syncthreads();

    float bv[CT];
#pragma unroll
    for (int t = 0; t < CT; ++t) bv[t] = bias[wc * (N / 2) + t * 16 + l15];

    floatx4 acc[2][CT];
#pragma unroll
    for (int rt = 0; rt < 2; ++rt)
#pragma unroll
        for (int t = 0; t < CT; ++t) acc[rt][t] = (floatx4){0.f, 0.f, 0.f, 0.f};

#pragma unroll
    for (int ks = 0; ks < KS; ++ks) {
        short8 b[CT];
#pragma unroll
        for (int t = 0; t < CT; ++t) {
            const int tg = wc * CT + t;
            b[t] = *reinterpret_cast<const short8*>(&WTf[((size_t)(tg * KS + ks) * 64 + lane) * 8]);
        }
        short8 a[2];
#pragma unroll
        for (int rt = 0; rt < 2; ++rt)
            a[rt] = *reinterpret_cast<const short8*>(&As[wr * 32 + rt * 16 + l15][ks * 32 + lk]);
#pragma unroll
        for (int rt = 0; rt < 2; ++rt)
#pragma unroll
            for (int t = 0; t < CT; ++t)
                acc[rt][t] = __builtin_amdgcn_mfma_f32_16x16x32_bf16(a[rt], b[t], acc[rt][t], 0, 0, 0);
    }

    const int rowg = (lane >> 4) * 4;
#pragma unroll
    for (int rt = 0; rt < 2; ++rt)
#pragma unroll
        for (int t = 0; t < CT; ++t)
#pragma unroll
            for (int j = 0; j < 4; ++j) {
                const int gr = r0 + wr * 32 + rt * 16 + rowg + j;
                if (gr < M)
                    C[(size_t)gr * N + wc * (N / 2) + t * 16 + l15] =
                        f32_to_bf16_bits(acc[rt][t][j] + bv[t]);
            }
}

// ---------------- FUSED: pull (64 nodes, D=128) -> relu -> GEMM ----------------
// Block = 1 bucket = 64 nodes, 8 waves (512 thr).
// Pull: 4 nodes per wave CONCURRENTLY (16 lanes x uint4 = full 256B row each),
// 2 rounds. Edge broadcast via width-16 shfl. Then MFMA from LDS.
template<int K, int N>
__global__ __launch_bounds__(512) void fused_pull_gemm(const unsigned int* __restrict__ h,
                                                       const int* __restrict__ row_ptr,
                                                       const unsigned int* __restrict__ csr_ew,
                                                       const short* __restrict__ WTf,
                                                       const float* __restrict__ bias,
                                                       short* __restrict__ C, int M)
{
    static_assert(K == 128, "pull input dim is 128");
    constexpr int KS   = K / 32;
    constexpr int LK   = K + 8;
    constexpr int COLT = 2;
    constexpr int WCG  = N / (COLT * 16);   // 4 (N=128) or 2 (N=64)
    constexpr int WRG  = 8 / WCG;           // 2 or 4
    constexpr int ROWT = 64 / (WRG * 16);   // 2 or 1

    __shared__ __align__(16) short As[64][LK];

    const int tid  = threadIdx.x;
    const int wave = tid >> 6;
    const int lane = tid & 63;
    const int q    = lane >> 4;
    const int l16  = lane & 15;
    const int r0   = blockIdx.x * 64;

    // ---- Pull: 2 rounds x 4 concurrent nodes per wave ----
#pragma unroll
    for (int rnd = 0; rnd < 2; ++rnd) {
        const int lrow = wave * 8 + rnd * 4 + q;
        const int node = r0 + lrow;
        int beg = 0, end = 0;
        if (node < M) { beg = row_ptr[node]; end = row_ptr[node + 1]; }

        float ax[4][4], ay[4][4];
#pragma unroll
        for (int u = 0; u < 4; ++u)
#pragma unroll
            for (int jj = 0; jj < 4; ++jj) { ax[u][jj] = 0.f; ay[u][jj] = 0.f; }

        for (int c = beg; c < end; c += 16) {
            const int idx = c + l16;
            const unsigned ew = (idx < end) ? csr_ew[idx] : 0u;
            const int cnt = min(16, end - c);
            for (int j = 0; j < cnt; j += 4) {
                unsigned e[4];
#pragma unroll
                for (int u = 0; u < 4; ++u) {
                    const unsigned v = __shfl(ew, j + u, 16);
                    e[u] = (j + u < cnt) ? v : 0u;       // pad: src=0, w=+0.0
                }
                uint4 p[4];
#pragma unroll
                for (int u = 0; u < 4; ++u)
                    p[u] = *reinterpret_cast<const uint4*>(&h[(size_t)(e[u] >> 16) * 64 + l16 * 4]);
#pragma unroll
                for (int u = 0; u < 4; ++u) {
                    const float wv = __int_as_float(e[u] << 16);
                    const unsigned* pp = reinterpret_cast<const unsigned*>(&p[u]);
#pragma unroll
                    for (int jj = 0; jj < 4; ++jj) {
                        ax[u][jj] = fmaf(__int_as_float(pp[jj] << 16), wv, ax[u][jj]);
                        ay[u][jj] = fmaf(__int_as_float(pp[jj] & 0xffff0000u), wv, ay[u][jj]);
                    }
                }
            }
        }

        if (node < M) {
            uint4 o;
            unsigned* ov = reinterpret_cast<unsigned*>(&o);
#pragma unroll
            for (int jj = 0; jj < 4; ++jj) {
                float axs = (ax[0][jj] + ax[1][jj]) + (ax[2][jj] + ax[3][jj]);
                float ays = (ay[0][jj] + ay[1][jj]) + (ay[2][jj] + ay[3][jj]);
                axs = fmaxf(axs, 0.f); ays = fmaxf(ays, 0.f);      // relu
                ov[jj] = (unsigned)(unsigned short)f32_to_bf16_bits(axs) |
                         ((unsigned)(unsigned short)f32_to_bf16_bits(ays) << 16);
            }
            *reinterpret_cast<uint4*>(&As[lrow][l16 * 8]) = o;
        }
    }
    __syncthreads();

    // ---- GEMM from LDS (8 waves) ----
    const int l15 = lane & 15;
    const int lk  = (lane >> 4) * 8;
    const int wr  = wave / WCG;
    const int wc  = wave % WCG;

    float bv[COLT];
#pragma unroll
    for (int t = 0; t < COLT; ++t) bv[t] = bias[wc * COLT * 16 + t * 16 + l15];

    floatx4 acc[ROWT][COLT];
#pragma unroll
    for (int rt = 0; rt < ROWT; ++rt)
#pragma unroll
        for (int t = 0; t < COLT; ++t) acc[rt][t] = (floatx4){0.f, 0.f, 0.f, 0.f};

#pragma unroll
    for (int ks = 0; ks < KS; ++ks) {
        short8 b[COLT];
#pragma unroll
        for (int t = 0; t < COLT; ++t) {
            const int tg = wc * COLT + t;
            b[t] = *reinterpret_cast<const short8*>(&WTf[((size_t)(tg * KS + ks) * 64 + lane) * 8]);
        }
        short8 a[ROWT];
#pragma unroll
        for (int rt = 0; rt < ROWT; ++rt)
            a[rt] = *reinterpret_cast<const short8*>(
                &As[wr * (ROWT * 16) + rt * 16 + l15][ks * 32 + lk]);
#pragma unroll
        for (int rt = 0; rt < ROWT; ++rt)
#pragma unroll
            for (int t = 0; t < COLT; ++t)
                acc[rt][t] = __builtin_amdgcn_mfma_f32_16x16x32_bf16(a[rt], b[t], acc[rt][t], 0, 0, 0);
    }

    const int rowg = (lane >> 4) * 4;
#pragma unroll
    for (int rt = 0; rt < ROWT; ++rt)
#pragma unroll
        for (int t = 0; t < COLT; ++t)
#pragma unroll
            for (int j = 0; j < 4; ++j) {
                const int gr = r0 + wr * (ROWT * 16) + rt * 16 + rowg + j;
                if (gr < M)
                    C[(size_t)gr * N + wc * COLT * 16 + t * 16 + l15] =
                        f32_to_bf16_bits(acc[rt][t][j] + bv[t]);
            }
}

// ---------------- W -> fragment-ordered bf16 WTf ----------------
__device__ inline void wt_frag(const float* __restrict__ W, short* __restrict__ out,
                               int K, int N, int u)
{
    const int lane = u & 63;
    const int rest = u >> 6;
    const int KS   = K >> 5;
    const int ks   = rest % KS;
    const int tg   = rest / KS;
    const int n    = tg * 16 + (lane & 15);
    const int kb   = ks * 32 + (lane >> 4) * 8;
    short8 s;
#pragma unroll
    for (int e = 0; e < 8; ++e) s[e] = f32_to_bf16_bits(W[(size_t)(kb + e) * N + n]);
    *reinterpret_cast<short8*>(&out[(size_t)u * 8]) = s;
}

// ================= prep: bin_hist (blocks 0..255) + wt transposes =================
__global__ __launch_bounds__(256) void prep_kernel(const int* __restrict__ dst,
                                                   int* __restrict__ hist_g, int E,
                                                   const float* __restrict__ W1, short* __restrict__ WT1,
                                                   const float* __restrict__ W2, short* __restrict__ WT2,
                                                   const float* __restrict__ W3, short* __restrict__ WT3)
{
    if (blockIdx.x < BIN_BLOCKS) {
        __shared__ int hist[NBUCK];
        for (int t = threadIdx.x; t < NBUCK; t += 256) hist[t] = 0;
        __syncthreads();
        const int chunk = (E + BIN_BLOCKS - 1) / BIN_BLOCKS;
        const int beg = blockIdx.x * chunk;
        const int end = min(beg + chunk, E);
        for (int i = beg + threadIdx.x; i < end; i += 256)
            atomicAdd(&hist[dst[i] >> BSHIFT], 1);
        __syncthreads();
        for (int t = threadIdx.x; t < NBUCK; t += 256)
            hist_g[blockIdx.x * NBUCK + t] = hist[t];
    } else {
        const int u = (blockIdx.x - BIN_BLOCKS) * 256 + threadIdx.x;
        if (u < 4096)             wt_frag(W1, WT1, 256, 128, u);
        else if (u < 4096 + 2048) wt_frag(W2, WT2, 128, 128, u - 4096);
        else if (u < 7168)        wt_frag(W3, WT3, 128, 64,  u - 6144);
    }
}

__global__ __launch_bounds__(256) void bin_scan_blocks(const int* __restrict__ hist_g,
                                                       int* __restrict__ blockbase,
                                                       int* __restrict__ tot)
{
    __shared__ int s[BIN_BLOCKS];
    const int b = blockIdx.x;
    const int t = threadIdx.x;
    const int v = hist_g[t * NBUCK + b];
    s[t] = v;
    __syncthreads();
#pragma unroll
    for (int off = 1; off < BIN_BLOCKS; off <<= 1) {
        const int tmp = (t >= off) ? s[t - off] : 0;
        __syncthreads();
        s[t] += tmp;
        __syncthreads();
    }
    blockbase[t * NBUCK + b] = s[t] - v;
    if (t == BIN_BLOCKS - 1) tot[b] = s[t];
}

__global__ __launch_bounds__(256) void bin_scan_tot(const int* __restrict__ tot,
                                                    int* __restrict__ bucket_base)
{
    __shared__ int psum[256];
    const int t = threadIdx.x;
    int vals[4];
    int s = 0;
#pragma unroll
    for (int j = 0; j < 4; ++j) {
        const int idx = t * 4 + j;
        vals[j] = (idx < NBUCK) ? tot[idx] : 0;
        s += vals[j];
    }
    psum[t] = s;
    __syncthreads();
#pragma unroll
    for (int off = 1; off < 256; off <<= 1) {
        const int tmp = (t >= off) ? psum[t - off] : 0;
        __syncthreads();
        psum[t] += tmp;
        __syncthreads();
    }
    int run = psum[t] - s;
#pragma unroll
    for (int j = 0; j < 4; ++j) {
        const int idx = t * 4 + j;
        if (idx < NBUCK) bucket_base[idx] = run;
        run += vals[j];
    }
    if (t == 255) bucket_base[NBUCK] = run;
}

__global__ __launch_bounds__(256) void bin_write(const int* __restrict__ src,
                                                 const int* __restrict__ dst,
                                                 const float* __restrict__ w,
                                                 const int* __restrict__ blockbase,
                                                 const int* __restrict__ bucket_base,
                                                 int2* __restrict__ tmp, int E)
{
    __shared__ int cur[NBUCK];
    for (int t = threadIdx.x; t < NBUCK; t += 256)
        cur[t] = bucket_base[t] + blockbase[blockIdx.x * NBUCK + t];
    __syncthreads();
    const int chunk = (E + BIN_BLOCKS - 1) / BIN_BLOCKS;
    const int beg = blockIdx.x * chunk;
    const int end = min(beg + chunk, E);
    for (int i = beg + threadIdx.x; i < end; i += 256) {
        const int d = dst[i];
        const int pos = atomicAdd(&cur[d >> BSHIFT], 1);
        tmp[pos] = make_int2((src[i] << BSHIFT) | (d & (BSIZE - 1)), __float_as_int(w[i]));
    }
}

// Pass D: one block per bucket. row_ptr + node-sorted packed 4B csr: (src<<16)|bf16(w)
__global__ __launch_bounds__(256) void fine_fill2(const int2* __restrict__ tmp,
                                                  const int* __restrict__ bucket_base,
                                                  unsigned int* __restrict__ csr_ew,
                                                  int* __restrict__ row_ptr)
{
    __shared__ int hist[BSIZE];
    __shared__ int basel[BSIZE];
    const int b    = blockIdx.x;
    const int t    = threadIdx.x;
    const int rbeg = bucket_base[b];
    const int rend = bucket_base[b + 1];

    if (t < BSIZE) hist[t] = 0;
    __syncthreads();
    for (int i = rbeg + t; i < rend; i += 256)
        atomicAdd(&hist[((unsigned)tmp[i].x) & (BSIZE - 1)], 1);
    __syncthreads();

    if (t < BSIZE) {
        const int v = hist[t];
        int inc = v;
#pragma unroll
        for (int off = 1; off < BSIZE; off <<= 1) {
            const int u = __shfl_up(inc, off, 64);
            if (t >= off) inc += u;
        }
        const int excl = rbeg + inc - v;
        basel[t] = excl;
        const int node = (b << BSHIFT) + t;
        if (node < N_NODES) row_ptr[node] = excl;
        if (b == NBUCK - 1 && t == 0) row_ptr[N_NODES] = bucket_base[NBUCK];
    }
    __syncthreads();

    for (int i = rbeg + t; i < rend; i += 256) {
        const int2 e = tmp[i];
        const unsigned ex = (unsigned)e.x;
        const int pos = atomicAdd(&basel[ex & (BSIZE - 1)], 1);
        const unsigned wb = (unsigned short)f32_to_bf16_bits(__int_as_float(e.y));
        csr_ew[pos] = ((ex >> BSHIFT) << 16) | wb;
    }
}

// ---------------- pull (bf16 h, D=64): 4 nodes per wave (16 lanes x uint2), f32 out ----------------
__global__ __launch_bounds__(256) void pull64_bf(const unsigned int* __restrict__ h,
                                                 const int* __restrict__ row_ptr,
                                                 const unsigned int* __restrict__ csr_ew,
                                                 float4* __restrict__ out, int n_nodes)
{
    const int wave = threadIdx.x >> 6;
    const int lane = threadIdx.x & 63;
    const int q    = lane >> 4;
    const int l16  = lane & 15;
    const int node = blockIdx.x * 16 + wave * 4 + q;

    int beg = 0, end = 0;
    if (node < n_nodes) { beg = row_ptr[node]; end = row_ptr[node + 1]; }

    float ax[4][2], ay[4][2];
#pragma unroll
    for (int u = 0; u < 4; ++u)
#pragma unroll
        for (int jj = 0; jj < 2; ++jj) { ax[u][jj] = 0.f; ay[u][jj] = 0.f; }

    for (int c = beg; c < end; c += 16) {
        const int idx = c + l16;
        const unsigned ew = (idx < end) ? csr_ew[idx] : 0u;
        const int cnt = min(16, end - c);
        for (int j = 0; j < cnt; j += 4) {
            unsigned e[4];
#pragma unroll
            for (int u = 0; u < 4; ++u) {
                const unsigned v = __shfl(ew, j + u, 16);
                e[u] = (j + u < cnt) ? v : 0u;
            }
            uint2 p[4];
#pragma unroll
            for (int u = 0; u < 4; ++u)
                p[u] = *reinterpret_cast<const uint2*>(&h[(size_t)(e[u] >> 16) * 32 + l16 * 2]);
#pragma unroll
            for (int u = 0; u < 4; ++u) {
                const float wv = __int_as_float(e[u] << 16);
                ax[u][0] = fmaf(__int_as_float(p[u].x << 16), wv, ax[u][0]);
                ay[u][0] = fmaf(__int_as_float(p[u].x & 0xffff0000u), wv, ay[u][0]);
                ax[u][1] = fmaf(__int_as_float(p[u].y << 16), wv, ax[u][1]);
                ay[u][1] = fmaf(__int_as_float(p[u].y & 0xffff0000u), wv, ay[u][1]);
            }
        }
    }

    if (node < n_nodes) {
        float4 o;
        o.x = (ax[0][0] + ax[1][0]) + (ax[2][0] + ax[3][0]);
        o.y = (ay[0][0] + ay[1][0]) + (ay[2][0] + ay[3][0]);
        o.z = (ax[0][1] + ax[1][1]) + (ax[2][1] + ax[3][1]);
        o.w = (ay[0][1] + ay[1][1]) + (ay[2][1] + ay[3][1]);
        out[(size_t)node * 16 + l16] = o;
    }
}

extern "C" void kernel_launch(void* const* d_in, const int* in_sizes, int n_in,
                              void* d_out, int out_size, void* d_ws, size_t ws_size,
                              hipStream_t stream)
{
    const float* x   = (const float*)d_in[0];
    const int*   src = (const int*)  d_in[1];
    const int*   dst = (const int*)  d_in[2];
    const float* w   = (const float*)d_in[3];
    const float* W1  = (const float*)d_in[4];
    const float* b1  = (const float*)d_in[5];
    const float* W2  = (const float*)d_in[6];
    const float* b2  = (const float*)d_in[7];
    const float* W3  = (const float*)d_in[8];
    const float* b3  = (const float*)d_in[9];

    const int E = in_sizes[1];
    const int M = N_NODES;

    // workspace layout
    short* hA  = (short*)d_ws;                        // M*128 bf16 (h1 / h3)
    short* hB  = hA + (size_t)M * 128;                // M*128 bf16 (h2)
    short* WT1 = hB + (size_t)M * 128;                // frag-ordered
    short* WT2 = WT1 + 128 * 256;
    short* WT3 = WT2 + 128 * 128;
    unsigned int* csr_ew = (unsigned int*)(WT3 + 64 * 128);  // E u32
    int2*  tmp_ew      = (int2*)(csr_ew + ((E + 1) & ~1));   // E pairs
    int*   row_ptr     = (int*)(tmp_ew + E);          // 50048
    int*   hist_g      = row_ptr + 50048;             // 256*782 -> pad 200704
    int*   blockbase   = hist_g + 200704;             // 256*782 -> pad 200704
    int*   bucket_base = blockbase + 200704;          // 783 -> pad 1024
    int*   tot         = bucket_base + 1024;          // 782 -> pad 1024

    // ---- build (weights + CSR), no global atomics ----
    prep_kernel<<<BIN_BLOCKS + 28, 256, 0, stream>>>(dst, hist_g, E, W1, WT1, W2, WT2, W3, WT3);
    bin_scan_blocks<<<NBUCK, BIN_BLOCKS, 0, stream>>>(hist_g, blockbase, tot);
    bin_scan_tot<<<1, 256, 0, stream>>>(tot, bucket_base);
    bin_write<<<BIN_BLOCKS, 256, 0, stream>>>(src, dst, w, blockbase, bucket_base, tmp_ew, E);
    fine_fill2<<<NBUCK, 256, 0, stream>>>(tmp_ew, bucket_base, csr_ew, row_ptr);

    // ---- Layer 1 GEMM: x @ W1 -> h1 (hA) ----
    mfma_gemm<256, 128, true><<<NBUCK, 256, 0, stream>>>(x, WT1, b1, hA, M);

    // ---- Fused: pull(h1) -> relu -> @W2 -> h2 (hB) ----
    fused_pull_gemm<128, 128><<<NBUCK, 512, 0, stream>>>((const unsigned int*)hA, row_ptr, csr_ew,
                                                         WT2, b2, hB, M);
    // ---- Fused: pull(h2) -> relu -> @W3 -> h3 (hA) ----
    fused_pull_gemm<128, 64><<<NBUCK, 512, 0, stream>>>((const unsigned int*)hB, row_ptr, csr_ew,
                                                        WT3, b3, hA, M);
    // ---- Final pull: out = segsum(h3) ----
    pull64_bf<<<(M + 15) / 16, 256, 0, stream>>>((const unsigned int*)hA, row_ptr, csr_ew,
                                                 (float4*)d_out, M);
}